// Round 7
// baseline (13732.880 us; speedup 1.0000x reference)
//
#include <hip/hip_runtime.h>
#include <math.h>

#define T_LEN 512
#define NB    32
#define EMB_  41
#define IN0_  42
#define HID_  800
#define G4_   3200
#define IN1_  1600
#define NU    20
#define NCH0  50    // layer-0 blocks per direction
#define NCH   100   // layer-1 consumer blocks per direction
#define XR    8     // xw ring depth
#define RH1   4     // h1 ring depth

typedef unsigned short u16;
typedef unsigned int   u32;
typedef unsigned long long u64;
typedef __attribute__((ext_vector_type(8))) short short8;
typedef __attribute__((ext_vector_type(4))) float f32x4;

__device__ __forceinline__ float bf2f(u16 v) {
    union { u32 u; float f; } c; c.u = ((u32)v) << 16; return c.f;
}
__device__ __forceinline__ u16 f2bf(float f) {
    union { float f; u32 u; } c; c.f = f;
    u32 r = (c.u + 0x7fffu + ((c.u >> 16) & 1u)) >> 16;
    return (u16)r;
}
__device__ __forceinline__ short cvt_hl(float v, int hl) {
    u16 hi = f2bf(v);
    return hl ? (short)f2bf(v - bf2f(hi)) : (short)hi;
}
__device__ __forceinline__ f32x4 mfma16(short8 a, short8 b, f32x4 c) {
    return __builtin_amdgcn_mfma_f32_16x16x32_bf16(a, b, c, 0, 0, 0);
}
__device__ __forceinline__ void astore(u64* p, u64 v) {
    __hip_atomic_store(p, v, __ATOMIC_RELAXED, __HIP_MEMORY_SCOPE_AGENT);
}
__device__ __forceinline__ u64 aload(const u64* p) {
    return __hip_atomic_load(p, __ATOMIC_RELAXED, __HIP_MEMORY_SCOPE_AGENT);
}
__device__ __forceinline__ int afload(const int* p) {
    return __hip_atomic_load(p, __ATOMIC_RELAXED, __HIP_MEMORY_SCOPE_AGENT);
}
__device__ __forceinline__ void afstore(int* p, int v) {
    __hip_atomic_store(p, v, __ATOMIC_RELAXED, __HIP_MEMORY_SCOPE_AGENT);
}

// Round-7 structure:
//  * lstm0: r6-proven (50 blocks/dir, T-paired chunks, per-t write-once h0f ring).
//  * lstm1: 250 blocks = 200 consumers + 50 x-producers.
//      - Producers (25/consumer-dir, 4 chunks each) compute the x-GEMM partial
//        fragments (identical frag values + op order as the old in-loop x-GEMM:
//        same wihL bf16 frags via precomputed wihB, same kc order, acc from 0)
//        and store f32x4 frags to ring xwf[s%XR] (agent-scope u64), then flag.
//        They depend only on h0f (static this dispatch) + consumer acks -> they
//        run ~XR steps ahead; consumers never wait on them in steady state.
//      - Consumers init their h-GEMM accumulators from xwf (agent-scope loads;
//        ring reuses addresses so plain cached loads would be stale) ->
//        BIT-IDENTICAL numerics to r1, with the x-GEMM off the serial path.
//      - h1 exchange: 4-slot ring (same-dir blocks are within 1 step of each
//        other due to all-to-all flags, so 4 slots cannot collide), atomic
//        staging loads (r0-proven).

// ---------------- wihB init: bf16 A-frag copy of w_ih1 (one-time) ----------------
__global__ __launch_bounds__(256)
void wihb_init(const float* __restrict__ wih1, u16* __restrict__ wihB)
{
    int gid = blockIdx.x*256 + threadIdx.x;   // one short8 per thread
    if (gid >= 2*100*2*50*64) return;
    int u = gid;
    const int l = u & 63; u >>= 6;
    const int idx = u % 50; u /= 50;
    const int p = u & 1; u >>= 1;
    const int ch = u % 100; u /= 100;
    const int dd = u;
    const int m = l & 15, g = p*2 + (m>>3), j = ch*8 + (m&7);
    const float* base = wih1 + ((size_t)(dd*G4_ + g*HID_ + j))*IN1_ + idx*32 + (l>>4)*8;
    float4 f0 = *(const float4*)base;
    float4 f1 = *(const float4*)(base + 4);
    short8 v;
    v[0]=(short)f2bf(f0.x); v[1]=(short)f2bf(f0.y); v[2]=(short)f2bf(f0.z); v[3]=(short)f2bf(f0.w);
    v[4]=(short)f2bf(f1.x); v[5]=(short)f2bf(f1.y); v[6]=(short)f2bf(f1.z); v[7]=(short)f2bf(f1.w);
    *(short8*)&wihB[(size_t)gid*8] = v;
}

// ---------------- Layer 0: r6-verbatim (100 blocks x 256 threads) ----------------
__global__ __launch_bounds__(256, 1)
void lstm0_persist(const float* __restrict__ seq, const float* __restrict__ wih0,
                   const float* __restrict__ whh0, const float* __restrict__ bias,
                   u16* __restrict__ h0f, int* __restrict__ flags)
{
    __shared__ __align__(16) float part[4096];
    __shared__ __align__(16) u16 stageB[25600];
    __shared__ __align__(16) float w0l[64*48];
    __shared__ __align__(16) float xsl[2][32*48];
    __shared__ u16 hpk[2][NB*8];
    const int tid = threadIdx.x;
    const int d = blockIdx.x / NCH0, ch = blockIdx.x % NCH0;
    const int w = tid >> 6, l = tid & 63;
    const int p = w & 1, hl = w >> 1;
    int* myflags = flags + d*128;

    short8 wreg[2][25];
    {
        const int m = l & 15, g = p*2 + (m>>3);
#pragma unroll
        for (int T = 0; T < 2; ++T) {
            const int j = (ch*2 + T)*8 + (m&7);
            const float* base = whh0 + ((size_t)(d*G4_ + g*HID_ + j))*HID_ + (l>>4)*8;
#pragma unroll
            for (int kc = 0; kc < 25; ++kc) {
                float4 f0 = *(const float4*)(base + kc*32);
                float4 f1 = *(const float4*)(base + kc*32 + 4);
                short8 v;
                v[0]=cvt_hl(f0.x,hl); v[1]=cvt_hl(f0.y,hl); v[2]=cvt_hl(f0.z,hl); v[3]=cvt_hl(f0.w,hl);
                v[4]=cvt_hl(f1.x,hl); v[5]=cvt_hl(f1.y,hl); v[6]=cvt_hl(f1.z,hl); v[7]=cvt_hl(f1.w,hl);
                wreg[T][kc] = v;
            }
        }
    }
    for (int idx = tid; idx < 64*EMB_; idx += 256) {
        int r = idx / EMB_, k = idx % EMB_;
        int ju_ = r >> 2, g = r & 3;
        w0l[r*48 + k] = wih0[((size_t)(d*G4_ + g*HID_ + ch*16 + ju_))*IN0_ + k];
    }
    const int ju = tid >> 5, b = tid & 31;
    const int nt = b >> 4, n = b & 15;
    float biasr[2][4], wpos[2][4];
#pragma unroll
    for (int T = 0; T < 2; ++T) {
        const int j = ch*16 + T*8 + ju;
#pragma unroll
        for (int g = 0; g < 4; ++g) {
            biasr[T][g] = bias[d*G4_ + g*HID_ + j];
            wpos[T][g]  = wih0[((size_t)(d*G4_ + g*HID_ + j))*IN0_ + EMB_];
        }
    }
    float creg[2] = {0.f, 0.f};
    __syncthreads();

    for (int s = 0; s < T_LEN; ++s) {
        const int t = d ? (T_LEN-1-s) : s;

        for (int idx = tid; idx < 32*EMB_; idx += 256)
            xsl[s&1][(idx/EMB_)*48 + idx%EMB_] = seq[(size_t)t*(NB*EMB_) + idx];

        if (s > 0 && tid < NCH0)
            while (afload(myflags + tid) < s) __builtin_amdgcn_s_sleep(1);
        __syncthreads();

        if (s == 0) {
#pragma unroll
            for (int q = 0; q < 25; ++q) ((u64*)stageB)[tid + q*256] = 0ull;
        } else {
            const int tprev = d ? (T_LEN - s) : (s - 1);
            const u64* src = (const u64*)(h0f + (size_t)tprev*51200) + d*6400;
            u64 tmp[25];
#pragma unroll
            for (int q = 0; q < 25; ++q) tmp[q] = src[tid + q*256];
#pragma unroll
            for (int q = 0; q < 25; ++q) ((u64*)stageB)[tid + q*256] = tmp[q];
        }
        __syncthreads();   // B

        f32x4 a00 = {0.f,0.f,0.f,0.f}, a01 = {0.f,0.f,0.f,0.f};
        f32x4 a10 = {0.f,0.f,0.f,0.f}, a11 = {0.f,0.f,0.f,0.f};
#pragma unroll
        for (int kc = 0; kc < 25; ++kc) {
            short8 b0 = *(const short8*)(stageB + kc*1024 + l*8);
            short8 b1 = *(const short8*)(stageB + kc*1024 + 512 + l*8);
            a00 = mfma16(wreg[0][kc], b0, a00);
            a01 = mfma16(wreg[0][kc], b1, a01);
            a10 = mfma16(wreg[1][kc], b0, a10);
            a11 = mfma16(wreg[1][kc], b1, a11);
        }
        {
            const int mrow = (l>>4)*4, nn = l & 15;
#pragma unroll
            for (int r = 0; r < 4; ++r) {
                part[((0*8 + (p*2+hl)*2 + 0)*16 + mrow + r)*16 + nn] = a00[r];
                part[((0*8 + (p*2+hl)*2 + 1)*16 + mrow + r)*16 + nn] = a01[r];
                part[((1*8 + (p*2+hl)*2 + 0)*16 + mrow + r)*16 + nn] = a10[r];
                part[((1*8 + (p*2+hl)*2 + 1)*16 + mrow + r)*16 + nn] = a11[r];
            }
        }
        __syncthreads();   // C

#pragma unroll
        for (int T = 0; T < 2; ++T) {
            float dot0 = 0.f, dot1 = 0.f, dot2 = 0.f, dot3 = 0.f;
            const float* wr = &w0l[(T*8 + ju)*4*48];
            const float* xr = &xsl[s&1][b*48];
#pragma unroll
            for (int k4 = 0; k4 < 40; k4 += 4) {
                float4 xk = *(const float4*)(xr + k4);
                float4 w0 = *(const float4*)(wr + 0*48 + k4);
                float4 w1 = *(const float4*)(wr + 1*48 + k4);
                float4 w2 = *(const float4*)(wr + 2*48 + k4);
                float4 w3 = *(const float4*)(wr + 3*48 + k4);
                dot0 += w0.x*xk.x + w0.y*xk.y + w0.z*xk.z + w0.w*xk.w;
                dot1 += w1.x*xk.x + w1.y*xk.y + w1.z*xk.z + w1.w*xk.w;
                dot2 += w2.x*xk.x + w2.y*xk.y + w2.z*xk.z + w2.w*xk.w;
                dot3 += w3.x*xk.x + w3.y*xk.y + w3.z*xk.z + w3.w*xk.w;
            }
            float xk = xr[40];
            dot0 += wr[0*48+40]*xk; dot1 += wr[1*48+40]*xk;
            dot2 += wr[2*48+40]*xk; dot3 += wr[3*48+40]*xk;
            float v[4] = {dot0, dot1, dot2, dot3};
#pragma unroll
            for (int g = 0; g < 4; ++g) {
                const int pp = g >> 1, m = (g & 1)*8 + ju;
                v[g] += part[((T*8 + (pp*2+0)*2 + nt)*16 + m)*16 + n]
                      + part[((T*8 + (pp*2+1)*2 + nt)*16 + m)*16 + n]
                      + biasr[T][g] + (float)t * wpos[T][g];
            }
            float ig = 1.f/(1.f + expf(-v[0]));
            float fg = 1.f/(1.f + expf(-v[1]));
            float gg = tanhf(v[2]);
            float og = 1.f/(1.f + expf(-v[3]));
            creg[T] = fg * creg[T] + ig * gg;
            hpk[T][b*8 + ju] = f2bf(og * tanhf(creg[T]));
        }
        __syncthreads();   // D

        if (tid < 128) {
            const int T = tid >> 6, tl = tid & 63;
            const int bb = tl >> 1, half = tl & 1;
            const u16* hp = &hpk[T][bb*8 + half*4];
            u64 pk = (u64)hp[0] | ((u64)hp[1]<<16) | ((u64)hp[2]<<32) | ((u64)hp[3]<<48);
            const int ch2 = ch*2 + T;
            const int ntb = bb >> 4, llb = ((ch2&3)<<4) | (bb&15);
            const int xoff = ((d*25 + (ch2>>2))*2 + ntb)*128 + llb*2 + half;
            astore((u64*)(h0f + (size_t)t*51200) + xoff, pk);
        }
        __syncthreads();   // E
        if (tid == 0) afstore(myflags + ch, s+1);
    }
}

// ---------------- Layer 1: 250 blocks = 200 consumers + 50 x-producers ----------------
__global__ __launch_bounds__(256, 1)
void lstm1_persist(const float* __restrict__ whh1, const float* __restrict__ bias,
                   const float* __restrict__ lin_w, const u16* __restrict__ h0f,
                   const u16* __restrict__ wihB, u16* __restrict__ h1f,
                   float* __restrict__ xwf, int* __restrict__ flags,
                   int* __restrict__ xwflag, int* __restrict__ ackf,
                   float* __restrict__ logits)
{
    __shared__ __align__(16) u16 stageB[25600];         // 51.2 KB
    __shared__ __align__(16) float part[2048];          // 8 KB
    __shared__ u16 hpk[NB*8];
    const int tid = threadIdx.x;
    const int w = tid >> 6, l = tid & 63;
    const int p = w & 1, hl = w >> 1;

    // ================= x-producer role =================
    if (blockIdx.x >= 200) {
        const int q = blockIdx.x - 200;       // 0..49
        const int dq = q / 25, gq = q % 25;   // consumer-dir, chunk group (4 chunks)
        int* acks = ackf + dq*100 + gq*4;
        const u16* wb = wihB + ((size_t)(dq*100 + gq*4)*2)*50*512;
        u64* dst = (u64*)xwf;

        for (int s = 0; s < T_LEN; ++s) {
            const int t = dq ? (T_LEN-1-s) : s;
            if (s >= XR && tid < 4)
                while (afload(acks + tid) < s - XR + 1) __builtin_amdgcn_s_sleep(1);
            __syncthreads();

            const u16* xb = h0f + (size_t)t*51200;
            f32x4 ac0[4], ac1[4];
#pragma unroll
            for (int c = 0; c < 4; ++c) {
                ac0[c] = (f32x4){0.f,0.f,0.f,0.f};
                ac1[c] = (f32x4){0.f,0.f,0.f,0.f};
            }
#pragma unroll 5
            for (int kc = 0; kc < 25; ++kc) {
                const int idx = hl*25 + kc;
                short8 b0 = *(const short8*)(xb + idx*1024 + l*8);
                short8 b1 = *(const short8*)(xb + idx*1024 + 512 + l*8);
#pragma unroll
                for (int c = 0; c < 4; ++c) {
                    short8 a = *(const short8*)(wb + (((size_t)c*2 + p)*50 + idx)*512 + l*8);
                    ac0[c] = mfma16(a, b0, ac0[c]);
                    ac1[c] = mfma16(a, b1, ac1[c]);
                }
            }
#pragma unroll
            for (int c = 0; c < 4; ++c) {
                const size_t chg = (size_t)dq*100 + gq*4 + c;
                size_t o0 = ((((((size_t)(s&(XR-1))*200 + chg)*2 + p)*2 + hl)*2 + 0)*64 + l)*2;
                union { f32x4 v; u64 qq[2]; } c0, c1;
                c0.v = ac0[c]; c1.v = ac1[c];
                astore(dst + o0,       c0.qq[0]);
                astore(dst + o0 + 1,   c0.qq[1]);
                astore(dst + o0 + 128, c1.qq[0]);   // nt=1 at +64 lanes*2 u64
                astore(dst + o0 + 129, c1.qq[1]);
            }
            __syncthreads();   // drains all waves' stores
            if (tid == 0) afstore(xwflag + q, s+1);
        }
        return;
    }

    // ================= consumer role =================
    const int d = blockIdx.x / NCH, ch = blockIdx.x % NCH;
    int* myflags = flags + d*128;
    int* myack   = ackf + d*100 + ch;
    const int myxwf = d*25 + (ch>>2);

    short8 wreg[25];
    {
        const int m = l & 15, g = p*2 + (m>>3), j = ch*8 + (m&7);
        const float* base = whh1 + ((size_t)(d*G4_ + g*HID_ + j))*HID_ + (l>>4)*8;
#pragma unroll
        for (int kc = 0; kc < 25; ++kc) {
            float4 f0 = *(const float4*)(base + kc*32);
            float4 f1 = *(const float4*)(base + kc*32 + 4);
            short8 v;
            v[0]=cvt_hl(f0.x,hl); v[1]=cvt_hl(f0.y,hl); v[2]=cvt_hl(f0.z,hl); v[3]=cvt_hl(f0.w,hl);
            v[4]=cvt_hl(f1.x,hl); v[5]=cvt_hl(f1.y,hl); v[6]=cvt_hl(f1.z,hl); v[7]=cvt_hl(f1.w,hl);
            wreg[kc] = v;
        }
    }
    // logit-owner constants + register-resident lin_w
    const int ol = tid >> 5, ln = tid & 31;
    const int lo = ch*7 + ol;
    const bool lown = (ol < 7) && (lo < NB*NU);
    int lofs = 0;
    float wlin[25];
    if (lown) {
        const int bb = lo / NU, uu = lo % NU;
        lofs = (bb >> 4)*512 + ((((ln >> 3) << 4) | (bb & 15)))*8 + (ln & 7);
        const float* wrow = lin_w + (size_t)uu*IN1_ + d*HID_ + ln;
#pragma unroll
        for (int i = 0; i < 25; ++i) wlin[i] = wrow[i*32];
    }
    const int ju = tid >> 5, b = tid & 31;
    const int j = ch*8 + ju;
    const int nt = b >> 4, n = b & 15;
    float biasr[4];
#pragma unroll
    for (int g = 0; g < 4; ++g) biasr[g] = bias[d*G4_ + g*HID_ + j];
    float creg = 0.f;
    __syncthreads();

    for (int s = 0; s < T_LEN; ++s) {
        if (s > 0 && tid < NCH)
            while (afload(myflags + tid) < s) __builtin_amdgcn_s_sleep(1);
        if (tid == 128)
            while (afload(xwflag + myxwf) < s+1) __builtin_amdgcn_s_sleep(1);
        __syncthreads();

        // x-partial fragments (agent-scope: ring addresses are reused)
        const u64* xwp = (const u64*)xwf +
            ((((((size_t)(s&(XR-1))*200 + d*100+ch)*2 + p)*2 + hl)*2 + 0)*64 + l)*2;
        u64 xq0 = aload(xwp), xq1 = aload(xwp + 1);
        u64 xq2 = aload(xwp + 128), xq3 = aload(xwp + 129);

        // stage h1(s-1) from the 4-slot ring (agent-scope loads, r0-proven)
        if (s == 0) {
#pragma unroll
            for (int q = 0; q < 25; ++q) ((u64*)stageB)[tid + q*256] = 0ull;
        } else {
            const u64* src = (const u64*)(h1f + (size_t)((s-1)&(RH1-1))*51200) + d*6400;
            u64 tmp[25];
#pragma unroll
            for (int q = 0; q < 25; ++q) tmp[q] = aload(src + tid + q*256);
#pragma unroll
            for (int q = 0; q < 25; ++q) ((u64*)stageB)[tid + q*256] = tmp[q];
        }
        __syncthreads();   // B

        f32x4 acc0, acc1;
        {
            union { u64 qq[2]; f32x4 v; } c0, c1;
            c0.qq[0] = xq0; c0.qq[1] = xq1;
            c1.qq[0] = xq2; c1.qq[1] = xq3;
            acc0 = c0.v; acc1 = c1.v;
        }
#pragma unroll 5
        for (int kc = 0; kc < 25; ++kc) {
            short8 b0 = *(const short8*)(stageB + kc*1024 + l*8);
            short8 b1 = *(const short8*)(stageB + kc*1024 + 512 + l*8);
            acc0 = mfma16(wreg[kc], b0, acc0);
            acc1 = mfma16(wreg[kc], b1, acc1);
        }
        {
            const int mrow = (l>>4)*4, nn = l & 15;
#pragma unroll
            for (int r = 0; r < 4; ++r) {
                part[(((p*2+hl)*2 + 0)*16 + mrow + r)*16 + nn] = acc0[r];
                part[(((p*2+hl)*2 + 1)*16 + mrow + r)*16 + nn] = acc1[r];
            }
        }
        __syncthreads();   // C

        float v[4];
#pragma unroll
        for (int g = 0; g < 4; ++g) {
            const int pp = g >> 1, m = (g & 1)*8 + ju;
            v[g] = part[(((pp*2+0)*2 + nt)*16 + m)*16 + n]
                 + part[(((pp*2+1)*2 + nt)*16 + m)*16 + n] + biasr[g];
        }
        float ig = 1.f/(1.f + expf(-v[0]));
        float fg = 1.f/(1.f + expf(-v[1]));
        float gg = tanhf(v[2]);
        float og = 1.f/(1.f + expf(-v[3]));
        creg = fg * creg + ig * gg;
        float hn = og * tanhf(creg);
        hpk[b*8 + ju] = f2bf(hn);
        __syncthreads();   // D

        if (tid < 64) {
            const int bb = tid >> 1, half = tid & 1;
            const u16* hp = &hpk[bb*8 + half*4];
            u64 pk = (u64)hp[0] | ((u64)hp[1]<<16) | ((u64)hp[2]<<32) | ((u64)hp[3]<<48);
            const int ntb = bb >> 4, llb = ((ch&3)<<4) | (bb&15);
            const int xoff = ((d*25 + (ch>>2))*2 + ntb)*128 + llb*2 + half;
            astore((u64*)(h1f + (size_t)(s&(RH1-1))*51200) + xoff, pk);
        }
        __syncthreads();   // E: drains h stores
        if (tid == 0) {
            afstore(myflags + ch, s+1);
            afstore(myack, s+1);       // xw ring ack (off critical path)
        }

        // distributed logits for h(tprev) from stageB (valid until next staging)
        if (s > 0 && lown) {
            float sum = 0.f;
#pragma unroll
            for (int i = 0; i < 25; ++i)
                sum += bf2f(stageB[i*1024 + lofs]) * wlin[i];
#pragma unroll
            for (int off2 = 16; off2; off2 >>= 1) sum += __shfl_down(sum, off2, 32);
            if (ln == 0) {
                const int tprev = d ? (T_LEN - s) : (s - 1);
                logits[((size_t)d*T_LEN + tprev)*640 + lo] = sum;
            }
        }
    }
    // tail: logits for the final h (slot (T_LEN-1)%RH1)
    if (tid < NCH)
        while (afload(myflags + tid) < T_LEN) __builtin_amdgcn_s_sleep(1);
    __syncthreads();
    {
        const u64* src = (const u64*)(h1f + (size_t)((T_LEN-1)&(RH1-1))*51200) + d*6400;
        u64 tmp[25];
#pragma unroll
        for (int q = 0; q < 25; ++q) tmp[q] = aload(src + tid + q*256);
#pragma unroll
        for (int q = 0; q < 25; ++q) ((u64*)stageB)[tid + q*256] = tmp[q];
    }
    __syncthreads();
    if (lown) {
        float sum = 0.f;
#pragma unroll
        for (int i = 0; i < 25; ++i)
            sum += bf2f(stageB[i*1024 + lofs]) * wlin[i];
#pragma unroll
        for (int off2 = 16; off2; off2 >>= 1) sum += __shfl_down(sum, off2, 32);
        if (ln == 0) {
            const int tprev = d ? 0 : (T_LEN - 1);
            logits[((size_t)d*T_LEN + tprev)*640 + lo] = sum;
        }
    }
}

// ---- sum dirs + lin_b -> softmax -> alphabet sin/cos mix; store (cosP, sinP) ----
__global__ __launch_bounds__(256)
void epilogue(const float* __restrict__ logits, const float* __restrict__ lin_b,
              const float* __restrict__ alphabet, float* __restrict__ cs)
{
    __shared__ float sa[NU*3], ca[NU*3], lb[NU];
    const int tid = threadIdx.x;
    if (tid < NU*3) { float al = alphabet[tid]; sa[tid] = sinf(al); ca[tid] = cosf(al); }
    if (tid < NU) lb[tid] = lin_b[tid];
    __syncthreads();
    const int row = blockIdx.x*256 + tid;   // t*NB + b
    if (row >= T_LEN*NB) return;
    const int t = row >> 5, b = row & 31;
    float lg[NU];
    float m = -1e30f;
#pragma unroll 4
    for (int u = 0; u < NU; ++u) {
        lg[u] = lb[u] + logits[(size_t)t*640 + b*NU + u]
                      + logits[((size_t)T_LEN + t)*640 + b*NU + u];
        m = fmaxf(m, lg[u]);
    }
    float ssum = 0.f;
#pragma unroll 4
    for (int u = 0; u < NU; ++u) { lg[u] = expf(lg[u] - m); ssum += lg[u]; }
    float inv = 1.f / ssum;
#pragma unroll
    for (int i = 0; i < 3; ++i) {
        float sv = 0.f, cv = 0.f;
#pragma unroll 4
        for (int u = 0; u < NU; ++u) {
            float sw = lg[u] * inv;
            sv += sw * sa[u*3 + i];
            cv += sw * ca[u*3 + i];
        }
        float rinv = rsqrtf(fmaxf(sv*sv + cv*cv, 1e-30f));
        *(float2*)(cs + ((size_t)row*3 + i)*2) = make_float2(cv*rinv, sv*rinv);
    }
}

// ---- sequential chain extension: one lane per molecule ----
__global__ __launch_bounds__(64)
void geometry(const float* __restrict__ cs, float* __restrict__ out)
{
    const int b = threadIdx.x;
    if (b >= NB) return;
    const float blen[3] = {1.329f, 1.459f, 1.525f};
    const float bang[3] = {2.034f, 2.119f, 1.937f};
    float sT[3], cT[3];
#pragma unroll
    for (int i = 0; i < 3; ++i) { sT[i] = sinf(bang[i]); cT[i] = cosf(bang[i]); }

    float Ax=0.f,Ay=0.f,Az=1.f, Bx=0.f,By=1.f,Bz=0.f, Cx=1.f,Cy=0.f,Cz=0.f;
    out[(0*NB + b)*3 + 0] = 0.f; out[(0*NB + b)*3 + 1] = 0.f; out[(0*NB + b)*3 + 2] = 1.f;
    out[(1*NB + b)*3 + 0] = 0.f; out[(1*NB + b)*3 + 1] = 1.f; out[(1*NB + b)*3 + 2] = 0.f;
    out[(2*NB + b)*3 + 0] = 1.f; out[(2*NB + b)*3 + 1] = 0.f; out[(2*NB + b)*3 + 2] = 0.f;

    for (int t = 1; t < T_LEN; ++t) {
        float2 pc[3];
#pragma unroll
        for (int i = 0; i < 3; ++i)
            pc[i] = *(const float2*)(cs + (((size_t)t*NB + b)*3 + i)*2);
#pragma unroll
        for (int i = 0; i < 3; ++i) {
            float R = blen[i];
            float d2x = -R*cT[i], d2y = R*pc[i].x*sT[i], d2z = R*pc[i].y*sT[i];
            float bcx = Cx-Bx, bcy = Cy-By, bcz = Cz-Bz;
            float inv = rsqrtf(bcx*bcx + bcy*bcy + bcz*bcz);
            bcx *= inv; bcy *= inv; bcz *= inv;
            float abx = Bx-Ax, aby = By-Ay, abz = Bz-Az;
            float nx = aby*bcz - abz*bcy;
            float ny = abz*bcx - abx*bcz;
            float nz = abx*bcy - aby*bcx;
            inv = rsqrtf(fmaxf(nx*nx + ny*ny + nz*nz, 1e-30f));
            nx *= inv; ny *= inv; nz *= inv;
            float mx = ny*bcz - nz*bcy;
            float my = nz*bcx - nx*bcz;
            float mz = nx*bcy - ny*bcx;
            float Dx = bcx*d2x + mx*d2y + nx*d2z + Cx;
            float Dy = bcy*d2x + my*d2y + ny*d2z + Cy;
            float Dz = bcz*d2x + mz*d2y + nz*d2z + Cz;
            Ax=Bx; Ay=By; Az=Bz; Bx=Cx; By=Cy; Bz=Cz; Cx=Dx; Cy=Dy; Cz=Dz;
            const int r = 3 + (t-1)*3 + i;
            out[((size_t)r*NB + b)*3 + 0] = Dx;
            out[((size_t)r*NB + b)*3 + 1] = Dy;
            out[((size_t)r*NB + b)*3 + 2] = Dz;
        }
    }
}

extern "C" void kernel_launch(void* const* d_in, const int* in_sizes, int n_in,
                              void* d_out, int out_size, void* d_ws, size_t ws_size,
                              hipStream_t stream)
{
    (void)in_sizes; (void)n_in; (void)out_size; (void)ws_size;
    const float* seq   = (const float*)d_in[0];
    const float* w_ih0 = (const float*)d_in[2];
    const float* w_hh0 = (const float*)d_in[3];
    const float* b0    = (const float*)d_in[4];
    const float* w_ih1 = (const float*)d_in[5];
    const float* w_hh1 = (const float*)d_in[6];
    const float* b1    = (const float*)d_in[7];
    const float* lin_w = (const float*)d_in[8];
    const float* lin_b = (const float*)d_in[9];
    const float* alpha = (const float*)d_in[10];

    // workspace (~89.4 MB)
    char* ws = (char*)d_ws;
    size_t off = 0;
    u16* h0f    = (u16*)(ws + off); off += 52428800ull;          // per-t write-once ring
    u16* wihB   = (u16*)(ws + off); off += 20480000ull;          // bf16 A-frag copy of w_ih1
    u16* h1f    = (u16*)(ws + off); off += (size_t)RH1*102400ull;// 4-slot h1 ring
    float* xwf  = (float*)(ws + off); off += (size_t)XR*200*8192ull; // xw frag ring
    int* flagsL0 = (int*)(ws + off); off += 1024ull;
    int* flagsL1 = (int*)(ws + off); off += 1024ull;
    int* xwflag  = (int*)(ws + off); off += 512ull;
    int* ackf    = (int*)(ws + off); off += 1024ull;
    float* logits = (float*)(ws + off); off += 2621440ull;
    float* cs = (float*)(ws + off); off += 393216ull;

    hipMemsetAsync(flagsL0, 0, 1024 + 1024 + 512 + 1024, stream);

    wihb_init<<<dim3(5000), dim3(256), 0, stream>>>(w_ih1, wihB);

    lstm0_persist<<<dim3(2*NCH0), dim3(256), 0, stream>>>(seq, w_ih0, w_hh0, b0, h0f, flagsL0);

    lstm1_persist<<<dim3(250), dim3(256), 0, stream>>>(w_hh1, b1, lin_w, h0f, wihB, h1f,
                                                       xwf, flagsL1, xwflag, ackf, logits);

    epilogue<<<dim3(64), dim3(256), 0, stream>>>(logits, lin_b, alpha, cs);
    geometry<<<dim3(1), dim3(64), 0, stream>>>(cs, (float*)d_out);
}

// Round 8
// 12923.654 us; speedup vs baseline: 1.0626x; 1.0626x over previous
//
#include <hip/hip_runtime.h>
#include <math.h>

#define T_LEN 512
#define NB    32
#define EMB_  41
#define IN0_  42
#define HID_  800
#define G4_   3200
#define IN1_  1600
#define NU    20
#define NCH0  50    // layer-0 blocks per direction
#define NCH   100   // layer-1 blocks per direction

typedef unsigned short u16;
typedef unsigned int   u32;
typedef unsigned long long u64;
typedef __attribute__((ext_vector_type(8))) short short8;
typedef __attribute__((ext_vector_type(4))) float f32x4;

__device__ __forceinline__ float bf2f(u16 v) {
    union { u32 u; float f; } c; c.u = ((u32)v) << 16; return c.f;
}
__device__ __forceinline__ u16 f2bf(float f) {
    union { float f; u32 u; } c; c.f = f;
    u32 r = (c.u + 0x7fffu + ((c.u >> 16) & 1u)) >> 16;
    return (u16)r;
}
__device__ __forceinline__ short cvt_hl(float v, int hl) {
    u16 hi = f2bf(v);
    return hl ? (short)f2bf(v - bf2f(hi)) : (short)hi;
}
__device__ __forceinline__ f32x4 mfma16(short8 a, short8 b, f32x4 c) {
    return __builtin_amdgcn_mfma_f32_16x16x32_bf16(a, b, c, 0, 0, 0);
}
__device__ __forceinline__ void astore(u64* p, u64 v) {
    __hip_atomic_store(p, v, __ATOMIC_RELAXED, __HIP_MEMORY_SCOPE_AGENT);
}
__device__ __forceinline__ int afload(const int* p) {
    return __hip_atomic_load(p, __ATOMIC_RELAXED, __HIP_MEMORY_SCOPE_AGENT);
}
__device__ __forceinline__ void afstore(int* p, int v) {
    __hip_atomic_store(p, v, __ATOMIC_RELAXED, __HIP_MEMORY_SCOPE_AGENT);
}

// Round-8 lstm1: 512-thread blocks, 4 compute waves (r1 recurrent chain, no
// x-GEMM/logits) + 4 x-waves. xw is BLOCK-LOCAL (r7's key miss): x-waves
// compute this block's xw(s+1) = wih1-chunk . h0(t(s+1)) into a 2-slot LDS
// ring, A-frags streamed from global wihB (bf16 precompute; L2-resident),
// B-frags plain loads of prior-dispatch h0f. Ring ordering needs NO new sync:
//   write slot (s+1)&1 happens in the stage phase of step s (post barrier A);
//   compute reads slot s&1 after barrier B(s). Every write/read pair in either
//   direction is separated by >=2 of the existing barriers (audited).
// Logits run on x-waves in the B->C window (stageB valid there, same data and
// relative timing as r1). Numerics bit-identical to r1: identical bf16 frag
// values (wihb_init = r1's wihL conversion), identical MFMA order (x-MFMAs
// kc 0..24 from acc=0, h-MFMAs continue the same acc; f32 transits LDS exact).

// ---------------- wihB init: bf16 A-frag copy of w_ih1 (one-time) ----------------
__global__ __launch_bounds__(256)
void wihb_init(const float* __restrict__ wih1, u16* __restrict__ wihB)
{
    int gid = blockIdx.x*256 + threadIdx.x;   // one short8 per thread
    if (gid >= 2*100*2*50*64) return;
    int u = gid;
    const int l = u & 63; u >>= 6;
    const int idx = u % 50; u /= 50;
    const int p = u & 1; u >>= 1;
    const int ch = u % 100; u /= 100;
    const int dd = u;
    const int m = l & 15, g = p*2 + (m>>3), j = ch*8 + (m&7);
    const float* base = wih1 + ((size_t)(dd*G4_ + g*HID_ + j))*IN1_ + idx*32 + (l>>4)*8;
    float4 f0 = *(const float4*)base;
    float4 f1 = *(const float4*)(base + 4);
    short8 v;
    v[0]=(short)f2bf(f0.x); v[1]=(short)f2bf(f0.y); v[2]=(short)f2bf(f0.z); v[3]=(short)f2bf(f0.w);
    v[4]=(short)f2bf(f1.x); v[5]=(short)f2bf(f1.y); v[6]=(short)f2bf(f1.z); v[7]=(short)f2bf(f1.w);
    *(short8*)&wihB[(size_t)gid*8] = v;
}

// ---------------- Layer 0: r6-verbatim (100 blocks x 256 threads) ----------------
__global__ __launch_bounds__(256, 1)
void lstm0_persist(const float* __restrict__ seq, const float* __restrict__ wih0,
                   const float* __restrict__ whh0, const float* __restrict__ bias,
                   u16* __restrict__ h0f, int* __restrict__ flags)
{
    __shared__ __align__(16) float part[4096];
    __shared__ __align__(16) u16 stageB[25600];
    __shared__ __align__(16) float w0l[64*48];
    __shared__ __align__(16) float xsl[2][32*48];
    __shared__ u16 hpk[2][NB*8];
    const int tid = threadIdx.x;
    const int d = blockIdx.x / NCH0, ch = blockIdx.x % NCH0;
    const int w = tid >> 6, l = tid & 63;
    const int p = w & 1, hl = w >> 1;
    int* myflags = flags + d*128;

    short8 wreg[2][25];
    {
        const int m = l & 15, g = p*2 + (m>>3);
#pragma unroll
        for (int T = 0; T < 2; ++T) {
            const int j = (ch*2 + T)*8 + (m&7);
            const float* base = whh0 + ((size_t)(d*G4_ + g*HID_ + j))*HID_ + (l>>4)*8;
#pragma unroll
            for (int kc = 0; kc < 25; ++kc) {
                float4 f0 = *(const float4*)(base + kc*32);
                float4 f1 = *(const float4*)(base + kc*32 + 4);
                short8 v;
                v[0]=cvt_hl(f0.x,hl); v[1]=cvt_hl(f0.y,hl); v[2]=cvt_hl(f0.z,hl); v[3]=cvt_hl(f0.w,hl);
                v[4]=cvt_hl(f1.x,hl); v[5]=cvt_hl(f1.y,hl); v[6]=cvt_hl(f1.z,hl); v[7]=cvt_hl(f1.w,hl);
                wreg[T][kc] = v;
            }
        }
    }
    for (int idx = tid; idx < 64*EMB_; idx += 256) {
        int r = idx / EMB_, k = idx % EMB_;
        int ju_ = r >> 2, g = r & 3;
        w0l[r*48 + k] = wih0[((size_t)(d*G4_ + g*HID_ + ch*16 + ju_))*IN0_ + k];
    }
    const int ju = tid >> 5, b = tid & 31;
    const int nt = b >> 4, n = b & 15;
    float biasr[2][4], wpos[2][4];
#pragma unroll
    for (int T = 0; T < 2; ++T) {
        const int j = ch*16 + T*8 + ju;
#pragma unroll
        for (int g = 0; g < 4; ++g) {
            biasr[T][g] = bias[d*G4_ + g*HID_ + j];
            wpos[T][g]  = wih0[((size_t)(d*G4_ + g*HID_ + j))*IN0_ + EMB_];
        }
    }
    float creg[2] = {0.f, 0.f};
    __syncthreads();

    for (int s = 0; s < T_LEN; ++s) {
        const int t = d ? (T_LEN-1-s) : s;

        for (int idx = tid; idx < 32*EMB_; idx += 256)
            xsl[s&1][(idx/EMB_)*48 + idx%EMB_] = seq[(size_t)t*(NB*EMB_) + idx];

        if (s > 0 && tid < NCH0)
            while (afload(myflags + tid) < s) __builtin_amdgcn_s_sleep(1);
        __syncthreads();

        if (s == 0) {
#pragma unroll
            for (int q = 0; q < 25; ++q) ((u64*)stageB)[tid + q*256] = 0ull;
        } else {
            const int tprev = d ? (T_LEN - s) : (s - 1);
            const u64* src = (const u64*)(h0f + (size_t)tprev*51200) + d*6400;
            u64 tmp[25];
#pragma unroll
            for (int q = 0; q < 25; ++q) tmp[q] = src[tid + q*256];
#pragma unroll
            for (int q = 0; q < 25; ++q) ((u64*)stageB)[tid + q*256] = tmp[q];
        }
        __syncthreads();   // B

        f32x4 a00 = {0.f,0.f,0.f,0.f}, a01 = {0.f,0.f,0.f,0.f};
        f32x4 a10 = {0.f,0.f,0.f,0.f}, a11 = {0.f,0.f,0.f,0.f};
#pragma unroll
        for (int kc = 0; kc < 25; ++kc) {
            short8 b0 = *(const short8*)(stageB + kc*1024 + l*8);
            short8 b1 = *(const short8*)(stageB + kc*1024 + 512 + l*8);
            a00 = mfma16(wreg[0][kc], b0, a00);
            a01 = mfma16(wreg[0][kc], b1, a01);
            a10 = mfma16(wreg[1][kc], b0, a10);
            a11 = mfma16(wreg[1][kc], b1, a11);
        }
        {
            const int mrow = (l>>4)*4, nn = l & 15;
#pragma unroll
            for (int r = 0; r < 4; ++r) {
                part[((0*8 + (p*2+hl)*2 + 0)*16 + mrow + r)*16 + nn] = a00[r];
                part[((0*8 + (p*2+hl)*2 + 1)*16 + mrow + r)*16 + nn] = a01[r];
                part[((1*8 + (p*2+hl)*2 + 0)*16 + mrow + r)*16 + nn] = a10[r];
                part[((1*8 + (p*2+hl)*2 + 1)*16 + mrow + r)*16 + nn] = a11[r];
            }
        }
        __syncthreads();   // C

#pragma unroll
        for (int T = 0; T < 2; ++T) {
            float dot0 = 0.f, dot1 = 0.f, dot2 = 0.f, dot3 = 0.f;
            const float* wr = &w0l[(T*8 + ju)*4*48];
            const float* xr = &xsl[s&1][b*48];
#pragma unroll
            for (int k4 = 0; k4 < 40; k4 += 4) {
                float4 xk = *(const float4*)(xr + k4);
                float4 w0 = *(const float4*)(wr + 0*48 + k4);
                float4 w1 = *(const float4*)(wr + 1*48 + k4);
                float4 w2 = *(const float4*)(wr + 2*48 + k4);
                float4 w3 = *(const float4*)(wr + 3*48 + k4);
                dot0 += w0.x*xk.x + w0.y*xk.y + w0.z*xk.z + w0.w*xk.w;
                dot1 += w1.x*xk.x + w1.y*xk.y + w1.z*xk.z + w1.w*xk.w;
                dot2 += w2.x*xk.x + w2.y*xk.y + w2.z*xk.z + w2.w*xk.w;
                dot3 += w3.x*xk.x + w3.y*xk.y + w3.z*xk.z + w3.w*xk.w;
            }
            float xk = xr[40];
            dot0 += wr[0*48+40]*xk; dot1 += wr[1*48+40]*xk;
            dot2 += wr[2*48+40]*xk; dot3 += wr[3*48+40]*xk;
            float v[4] = {dot0, dot1, dot2, dot3};
#pragma unroll
            for (int g = 0; g < 4; ++g) {
                const int pp = g >> 1, m = (g & 1)*8 + ju;
                v[g] += part[((T*8 + (pp*2+0)*2 + nt)*16 + m)*16 + n]
                      + part[((T*8 + (pp*2+1)*2 + nt)*16 + m)*16 + n]
                      + biasr[T][g] + (float)t * wpos[T][g];
            }
            float ig = 1.f/(1.f + expf(-v[0]));
            float fg = 1.f/(1.f + expf(-v[1]));
            float gg = tanhf(v[2]);
            float og = 1.f/(1.f + expf(-v[3]));
            creg[T] = fg * creg[T] + ig * gg;
            hpk[T][b*8 + ju] = f2bf(og * tanhf(creg[T]));
        }
        __syncthreads();   // D

        if (tid < 128) {
            const int T = tid >> 6, tl = tid & 63;
            const int bb = tl >> 1, half = tl & 1;
            const u16* hp = &hpk[T][bb*8 + half*4];
            u64 pk = (u64)hp[0] | ((u64)hp[1]<<16) | ((u64)hp[2]<<32) | ((u64)hp[3]<<48);
            const int ch2 = ch*2 + T;
            const int ntb = bb >> 4, llb = ((ch2&3)<<4) | (bb&15);
            const int xoff = ((d*25 + (ch2>>2))*2 + ntb)*128 + llb*2 + half;
            astore((u64*)(h0f + (size_t)t*51200) + xoff, pk);
        }
        __syncthreads();   // E
        if (tid == 0) afstore(myflags + ch, s+1);
    }
}

// ---------------- Layer 1: 200 blocks x 512 threads (4 compute + 4 x waves) ----------------
__global__ __launch_bounds__(512, 2)
void lstm1_persist(const float* __restrict__ whh1, const float* __restrict__ bias,
                   const float* __restrict__ lin_w, const u16* __restrict__ h0f,
                   const u16* __restrict__ wihB, u16* __restrict__ h1f,
                   int* __restrict__ flags, float* __restrict__ logits)
{
    __shared__ __align__(16) u16 stageB[25600];         // 51.2 KB
    __shared__ __align__(16) float part[2048];          // 8 KB
    __shared__ __align__(16) float xwr[2][2048];        // 16 KB xw ring (x->compute)
    __shared__ u16 hpk[NB*8];
    const int tid = threadIdx.x;
    const int d = blockIdx.x / NCH, ch = blockIdx.x % NCH;
    const int w = tid >> 6, l = tid & 63;
    const bool comp = w < 4;
    const int p = w & 1, hl = (w >> 1) & 1;             // compute mapping (w 0..3)
    const int xw_ = w - 4;                              // x mapping (w 4..7)
    const int xp = xw_ & 1, xhl = (xw_ >> 1) & 1;
    int* myflags = flags + d*128;

    short8 wreg[25];        // compute only: whh1 hi/lo frags
    if (comp) {
        const int m = l & 15, g = p*2 + (m>>3), j = ch*8 + (m&7);
        const float* base = whh1 + ((size_t)(d*G4_ + g*HID_ + j))*HID_ + (l>>4)*8;
#pragma unroll
        for (int kc = 0; kc < 25; ++kc) {
            float4 f0 = *(const float4*)(base + kc*32);
            float4 f1 = *(const float4*)(base + kc*32 + 4);
            short8 v;
            v[0]=cvt_hl(f0.x,hl); v[1]=cvt_hl(f0.y,hl); v[2]=cvt_hl(f0.z,hl); v[3]=cvt_hl(f0.w,hl);
            v[4]=cvt_hl(f1.x,hl); v[5]=cvt_hl(f1.y,hl); v[6]=cvt_hl(f1.z,hl); v[7]=cvt_hl(f1.w,hl);
            wreg[kc] = v;
        }
    }
    // x-wave A-frag base (global, L2-resident) — values identical to r1's wihL
    const u16* wb = wihB + ((size_t)((d*100 + ch)*2 + xp)*50)*512;

    // logit owners live on x-waves (xt = tid-256; 7 owners of 32 lanes each)
    const int xt = tid & 255;
    const int ol = xt >> 5, ln = xt & 31;
    const int lo = ch*7 + ol;
    const bool lown = (!comp) && (ol < 7) && (lo < NB*NU);
    int lofs = 0;
    float wlin[25];
    if (lown) {
        const int bb = lo / NU, uu = lo % NU;
        lofs = (bb >> 4)*512 + ((((ln >> 3) << 4) | (bb & 15)))*8 + (ln & 7);
        const float* wrow = lin_w + (size_t)uu*IN1_ + d*HID_ + ln;
#pragma unroll
        for (int i = 0; i < 25; ++i) wlin[i] = wrow[i*32];
    }
    const int ju = tid >> 5, b = tid & 31;   // gate mapping (compute: tid<256)
    const int nt = b >> 4, n = b & 15;
    float biasr[4];
    if (comp) {
        const int j = ch*8 + ju;
#pragma unroll
        for (int g = 0; g < 4; ++g) biasr[g] = bias[d*G4_ + g*HID_ + j];
    }
    float creg = 0.f;
    __syncthreads();

    // preamble: x-waves fill xw ring slot 0 (h0f is prior-dispatch data)
    if (!comp) {
        const int t0 = d ? (T_LEN-1) : 0;
        const u16* xb = h0f + (size_t)t0*51200;
        f32x4 a0 = {0.f,0.f,0.f,0.f}, a1 = {0.f,0.f,0.f,0.f};
#pragma unroll 5
        for (int kc = 0; kc < 25; ++kc) {
            const int idx = xhl*25 + kc;
            short8 a  = *(const short8*)(wb + idx*512 + l*8);
            short8 b0 = *(const short8*)(xb + idx*1024 + l*8);
            short8 b1 = *(const short8*)(xb + idx*1024 + 512 + l*8);
            a0 = mfma16(a, b0, a0);
            a1 = mfma16(a, b1, a1);
        }
        *(f32x4*)&xwr[0][((xp*2+xhl)*2 + 0)*256 + l*4] = a0;
        *(f32x4*)&xwr[0][((xp*2+xhl)*2 + 1)*256 + l*4] = a1;
    }
    __syncthreads();

    for (int s = 0; s < T_LEN; ++s) {
        const int t = d ? (T_LEN-1-s) : s;

        if (comp && s > 0 && tid < NCH)
            while (afload(myflags + tid) < s) __builtin_amdgcn_s_sleep(1);
        __syncthreads();   // A

        if (comp) {
            // stage h1(s-1) from the per-t write-once ring (plain loads)
            if (s == 0) {
#pragma unroll
                for (int q = 0; q < 25; ++q) ((u64*)stageB)[tid + q*256] = 0ull;
            } else {
                const int tprev = d ? (T_LEN - s) : (s - 1);
                const u64* src = (const u64*)(h1f + (size_t)tprev*51200) + d*6400;
                u64 tmp[25];
#pragma unroll
                for (int q = 0; q < 25; ++q) tmp[q] = src[tid + q*256];
#pragma unroll
                for (int q = 0; q < 25; ++q) ((u64*)stageB)[tid + q*256] = tmp[q];
            }
        } else if (s + 1 < T_LEN) {
            // xw(s+1) -> ring slot (s+1)&1 (read at s+1 post-B: >=2 barriers away)
            const int t1 = d ? (T_LEN-1-(s+1)) : (s+1);
            const u16* xb = h0f + (size_t)t1*51200;
            f32x4 a0 = {0.f,0.f,0.f,0.f}, a1 = {0.f,0.f,0.f,0.f};
#pragma unroll 5
            for (int kc = 0; kc < 25; ++kc) {
                const int idx = xhl*25 + kc;
                short8 a  = *(const short8*)(wb + idx*512 + l*8);
                short8 b0 = *(const short8*)(xb + idx*1024 + l*8);
                short8 b1 = *(const short8*)(xb + idx*1024 + 512 + l*8);
                a0 = mfma16(a, b0, a0);
                a1 = mfma16(a, b1, a1);
            }
            *(f32x4*)&xwr[(s+1)&1][((xp*2+xhl)*2 + 0)*256 + l*4] = a0;
            *(f32x4*)&xwr[(s+1)&1][((xp*2+xhl)*2 + 1)*256 + l*4] = a1;
        }
        __syncthreads();   // B

        if (comp) {
            f32x4 acc0 = *(const f32x4*)&xwr[s&1][((p*2+hl)*2 + 0)*256 + l*4];
            f32x4 acc1 = *(const f32x4*)&xwr[s&1][((p*2+hl)*2 + 1)*256 + l*4];
#pragma unroll 5
            for (int kc = 0; kc < 25; ++kc) {
                short8 b0 = *(const short8*)(stageB + kc*1024 + l*8);
                short8 b1 = *(const short8*)(stageB + kc*1024 + 512 + l*8);
                acc0 = mfma16(wreg[kc], b0, acc0);
                acc1 = mfma16(wreg[kc], b1, acc1);
            }
            const int mrow = (l>>4)*4, nn = l & 15;
#pragma unroll
            for (int r = 0; r < 4; ++r) {
                part[(((p*2+hl)*2 + 0)*16 + mrow + r)*16 + nn] = acc0[r];
                part[(((p*2+hl)*2 + 1)*16 + mrow + r)*16 + nn] = acc1[r];
            }
        } else if (s > 0 && lown) {
            // logits for h1(s-1) from stageB (valid post-B until next staging)
            float sum = 0.f;
#pragma unroll
            for (int i = 0; i < 25; ++i)
                sum += bf2f(stageB[i*1024 + lofs]) * wlin[i];
#pragma unroll
            for (int off2 = 16; off2; off2 >>= 1) sum += __shfl_down(sum, off2, 32);
            if (ln == 0) {
                const int tprev = d ? (T_LEN - s) : (s - 1);
                logits[((size_t)d*T_LEN + tprev)*640 + lo] = sum;
            }
        }
        __syncthreads();   // C

        if (comp) {
            float v[4];
#pragma unroll
            for (int g = 0; g < 4; ++g) {
                const int pp = g >> 1, m = (g & 1)*8 + ju;
                v[g] = part[(((pp*2+0)*2 + nt)*16 + m)*16 + n]
                     + part[(((pp*2+1)*2 + nt)*16 + m)*16 + n] + biasr[g];
            }
            float ig = 1.f/(1.f + expf(-v[0]));
            float fg = 1.f/(1.f + expf(-v[1]));
            float gg = tanhf(v[2]);
            float og = 1.f/(1.f + expf(-v[3]));
            creg = fg * creg + ig * gg;
            hpk[b*8 + ju] = f2bf(og * tanhf(creg));
        }
        __syncthreads();   // D

        if (tid < 64) {
            const int bb = tid >> 1, half = tid & 1;
            const u16* hp = &hpk[bb*8 + half*4];
            u64 pk = (u64)hp[0] | ((u64)hp[1]<<16) | ((u64)hp[2]<<32) | ((u64)hp[3]<<48);
            const int ntb = bb >> 4, llb = ((ch&3)<<4) | (bb&15);
            const int xoff = ((d*25 + (ch>>2))*2 + ntb)*128 + llb*2 + half;
            astore((u64*)(h1f + (size_t)t*51200) + xoff, pk);
        }
        __syncthreads();   // E: drains h stores
        if (tid == 0) afstore(myflags + ch, s+1);
    }
    // tail: logits for the final staged h1
    if (tid < NCH)
        while (afload(myflags + tid) < T_LEN) __builtin_amdgcn_s_sleep(1);
    __syncthreads();
    if (comp) {
        const int tlast = d ? 0 : (T_LEN - 1);
        const u64* src = (const u64*)(h1f + (size_t)tlast*51200) + d*6400;
        u64 tmp[25];
#pragma unroll
        for (int q = 0; q < 25; ++q) tmp[q] = src[tid + q*256];
#pragma unroll
        for (int q = 0; q < 25; ++q) ((u64*)stageB)[tid + q*256] = tmp[q];
    }
    __syncthreads();
    if (lown) {
        float sum = 0.f;
#pragma unroll
        for (int i = 0; i < 25; ++i)
            sum += bf2f(stageB[i*1024 + lofs]) * wlin[i];
#pragma unroll
        for (int off2 = 16; off2; off2 >>= 1) sum += __shfl_down(sum, off2, 32);
        if (ln == 0) {
            const int tprev = d ? 0 : (T_LEN - 1);
            logits[((size_t)d*T_LEN + tprev)*640 + lo] = sum;
        }
    }
}

// ---- sum dirs + lin_b -> softmax -> alphabet sin/cos mix; store (cosP, sinP) ----
__global__ __launch_bounds__(256)
void epilogue(const float* __restrict__ logits, const float* __restrict__ lin_b,
              const float* __restrict__ alphabet, float* __restrict__ cs)
{
    __shared__ float sa[NU*3], ca[NU*3], lb[NU];
    const int tid = threadIdx.x;
    if (tid < NU*3) { float al = alphabet[tid]; sa[tid] = sinf(al); ca[tid] = cosf(al); }
    if (tid < NU) lb[tid] = lin_b[tid];
    __syncthreads();
    const int row = blockIdx.x*256 + tid;   // t*NB + b
    if (row >= T_LEN*NB) return;
    const int t = row >> 5, b = row & 31;
    float lg[NU];
    float m = -1e30f;
#pragma unroll 4
    for (int u = 0; u < NU; ++u) {
        lg[u] = lb[u] + logits[(size_t)t*640 + b*NU + u]
                      + logits[((size_t)T_LEN + t)*640 + b*NU + u];
        m = fmaxf(m, lg[u]);
    }
    float ssum = 0.f;
#pragma unroll 4
    for (int u = 0; u < NU; ++u) { lg[u] = expf(lg[u] - m); ssum += lg[u]; }
    float inv = 1.f / ssum;
#pragma unroll
    for (int i = 0; i < 3; ++i) {
        float sv = 0.f, cv = 0.f;
#pragma unroll 4
        for (int u = 0; u < NU; ++u) {
            float sw = lg[u] * inv;
            sv += sw * sa[u*3 + i];
            cv += sw * ca[u*3 + i];
        }
        float rinv = rsqrtf(fmaxf(sv*sv + cv*cv, 1e-30f));
        *(float2*)(cs + ((size_t)row*3 + i)*2) = make_float2(cv*rinv, sv*rinv);
    }
}

// ---- sequential chain extension: one lane per molecule ----
__global__ __launch_bounds__(64)
void geometry(const float* __restrict__ cs, float* __restrict__ out)
{
    const int b = threadIdx.x;
    if (b >= NB) return;
    const float blen[3] = {1.329f, 1.459f, 1.525f};
    const float bang[3] = {2.034f, 2.119f, 1.937f};
    float sT[3], cT[3];
#pragma unroll
    for (int i = 0; i < 3; ++i) { sT[i] = sinf(bang[i]); cT[i] = cosf(bang[i]); }

    float Ax=0.f,Ay=0.f,Az=1.f, Bx=0.f,By=1.f,Bz=0.f, Cx=1.f,Cy=0.f,Cz=0.f;
    out[(0*NB + b)*3 + 0] = 0.f; out[(0*NB + b)*3 + 1] = 0.f; out[(0*NB + b)*3 + 2] = 1.f;
    out[(1*NB + b)*3 + 0] = 0.f; out[(1*NB + b)*3 + 1] = 1.f; out[(1*NB + b)*3 + 2] = 0.f;
    out[(2*NB + b)*3 + 0] = 1.f; out[(2*NB + b)*3 + 1] = 0.f; out[(2*NB + b)*3 + 2] = 0.f;

    for (int t = 1; t < T_LEN; ++t) {
        float2 pc[3];
#pragma unroll
        for (int i = 0; i < 3; ++i)
            pc[i] = *(const float2*)(cs + (((size_t)t*NB + b)*3 + i)*2);
#pragma unroll
        for (int i = 0; i < 3; ++i) {
            float R = blen[i];
            float d2x = -R*cT[i], d2y = R*pc[i].x*sT[i], d2z = R*pc[i].y*sT[i];
            float bcx = Cx-Bx, bcy = Cy-By, bcz = Cz-Bz;
            float inv = rsqrtf(bcx*bcx + bcy*bcy + bcz*bcz);
            bcx *= inv; bcy *= inv; bcz *= inv;
            float abx = Bx-Ax, aby = By-Ay, abz = Bz-Az;
            float nx = aby*bcz - abz*bcy;
            float ny = abz*bcx - abx*bcz;
            float nz = abx*bcy - aby*bcx;
            inv = rsqrtf(fmaxf(nx*nx + ny*ny + nz*nz, 1e-30f));
            nx *= inv; ny *= inv; nz *= inv;
            float mx = ny*bcz - nz*bcy;
            float my = nz*bcx - nx*bcz;
            float mz = nx*bcy - ny*bcx;
            float Dx = bcx*d2x + mx*d2y + nx*d2z + Cx;
            float Dy = bcy*d2x + my*d2y + ny*d2z + Cy;
            float Dz = bcz*d2x + mz*d2y + nz*d2z + Cz;
            Ax=Bx; Ay=By; Az=Bz; Bx=Cx; By=Cy; Bz=Cz; Cx=Dx; Cy=Dy; Cz=Dz;
            const int r = 3 + (t-1)*3 + i;
            out[((size_t)r*NB + b)*3 + 0] = Dx;
            out[((size_t)r*NB + b)*3 + 1] = Dy;
            out[((size_t)r*NB + b)*3 + 2] = Dz;
        }
    }
}

extern "C" void kernel_launch(void* const* d_in, const int* in_sizes, int n_in,
                              void* d_out, int out_size, void* d_ws, size_t ws_size,
                              hipStream_t stream)
{
    (void)in_sizes; (void)n_in; (void)out_size; (void)ws_size;
    const float* seq   = (const float*)d_in[0];
    const float* w_ih0 = (const float*)d_in[2];
    const float* w_hh0 = (const float*)d_in[3];
    const float* b0    = (const float*)d_in[4];
    const float* w_ih1 = (const float*)d_in[5];
    const float* w_hh1 = (const float*)d_in[6];
    const float* b1    = (const float*)d_in[7];
    const float* lin_w = (const float*)d_in[8];
    const float* lin_b = (const float*)d_in[9];
    const float* alpha = (const float*)d_in[10];

    // workspace (~128.4 MB)
    char* ws = (char*)d_ws;
    size_t off = 0;
    u16* h0f    = (u16*)(ws + off); off += 52428800ull;   // per-t write-once ring
    u16* h1f    = (u16*)(ws + off); off += 52428800ull;   // per-t write-once ring
    u16* wihB   = (u16*)(ws + off); off += 20480000ull;   // bf16 A-frag copy of w_ih1
    int* flagsL0 = (int*)(ws + off); off += 1024ull;      // 2 dirs x 128 ints
    int* flagsL1 = (int*)(ws + off); off += 1024ull;
    float* logits = (float*)(ws + off); off += 2621440ull;
    float* cs = (float*)(ws + off); off += 393216ull;

    hipMemsetAsync(flagsL0, 0, 2048, stream);   // both flag arrays

    wihb_init<<<dim3(5000), dim3(256), 0, stream>>>(w_ih1, wihB);

    lstm0_persist<<<dim3(2*NCH0), dim3(256), 0, stream>>>(seq, w_ih0, w_hh0, b0, h0f, flagsL0);

    lstm1_persist<<<dim3(2*NCH), dim3(512), 0, stream>>>(w_hh1, b1, lin_w, h0f, wihB, h1f,
                                                         flagsL1, logits);

    epilogue<<<dim3(64), dim3(256), 0, stream>>>(logits, lin_b, alpha, cs);
    geometry<<<dim3(1), dim3(64), 0, stream>>>(cs, (float*)d_out);
}

// Round 9
// 12271.080 us; speedup vs baseline: 1.1191x; 1.0532x over previous
//
#include <hip/hip_runtime.h>
#include <math.h>

#define T_LEN 512
#define NB    32
#define EMB_  41
#define IN0_  42
#define HID_  800
#define G4_   3200
#define IN1_  1600
#define NU    20
#define NCH0  50    // layer-0 blocks per direction
#define NCH   100   // layer-1 blocks per direction

typedef unsigned short u16;
typedef unsigned int   u32;
typedef unsigned long long u64;
typedef __attribute__((ext_vector_type(8))) short short8;
typedef __attribute__((ext_vector_type(4))) float f32x4;

__device__ __forceinline__ float bf2f(u16 v) {
    union { u32 u; float f; } c; c.u = ((u32)v) << 16; return c.f;
}
__device__ __forceinline__ u16 f2bf(float f) {
    union { float f; u32 u; } c; c.f = f;
    u32 r = (c.u + 0x7fffu + ((c.u >> 16) & 1u)) >> 16;
    return (u16)r;
}
__device__ __forceinline__ short cvt_hl(float v, int hl) {
    u16 hi = f2bf(v);
    return hl ? (short)f2bf(v - bf2f(hi)) : (short)hi;
}
__device__ __forceinline__ f32x4 mfma16(short8 a, short8 b, f32x4 c) {
    return __builtin_amdgcn_mfma_f32_16x16x32_bf16(a, b, c, 0, 0, 0);
}
__device__ __forceinline__ void astore(u64* p, u64 v) {
    __hip_atomic_store(p, v, __ATOMIC_RELAXED, __HIP_MEMORY_SCOPE_AGENT);
}
__device__ __forceinline__ int afload(const int* p) {
    return __hip_atomic_load(p, __ATOMIC_RELAXED, __HIP_MEMORY_SCOPE_AGENT);
}
__device__ __forceinline__ void afstore(int* p, int v) {
    __hip_atomic_store(p, v, __ATOMIC_RELAXED, __HIP_MEMORY_SCOPE_AGENT);
}

// Round-9 lstm1 (256 threads, r1 skeleton, bit-identical numerics):
//  * LDS swap: wihL (step-invariant w_ih1 frags, 100 KB) -> global wihB
//    (bf16 precompute, proven correct in r7/r8; L2-resident: ~25 blocks/XCD
//    x 100 KB = 2.5 MB < 4 MB L2, re-read every step so it stays hot).
//    Freed 100 KB becomes xstage: the full h0f[t] slab (102.4 KB, both dirs),
//    staged per step as a 50-u64/thread all-in-flight burst overlapped with
//    the h1 stage burst — replacing r1's latency-chained in-MFMA-loop x loads.
//    LDS total unchanged: 102400+51200+8192+512 = 162304 B (fits 160 KiB).
//  * MFMA values & order identical to r1: acc=0 -> x-MFMAs (A=wihB frags ==
//    old wihL values, B=xstage == old xb values, idx=hl*25+kc, kc 0..24) ->
//    h-MFMAs (wreg, stageB). Gates/part/store identical.
//  * wlin registers -> per-use global reads of lin_w (L2-hot, post-flag
//    shadow) to keep peak VGPR under the spill cliff (rule: 256 thr only;
//    512-thr spills wreg — r3/r8 twice-confirmed).

// ---------------- wihB init: bf16 A-frag copy of w_ih1 (one-time) ----------------
__global__ __launch_bounds__(256)
void wihb_init(const float* __restrict__ wih1, u16* __restrict__ wihB)
{
    int gid = blockIdx.x*256 + threadIdx.x;   // one short8 per thread
    if (gid >= 2*100*2*50*64) return;
    int u = gid;
    const int l = u & 63; u >>= 6;
    const int idx = u % 50; u /= 50;
    const int p = u & 1; u >>= 1;
    const int ch = u % 100; u /= 100;
    const int dd = u;
    const int m = l & 15, g = p*2 + (m>>3), j = ch*8 + (m&7);
    const float* base = wih1 + ((size_t)(dd*G4_ + g*HID_ + j))*IN1_ + idx*32 + (l>>4)*8;
    float4 f0 = *(const float4*)base;
    float4 f1 = *(const float4*)(base + 4);
    short8 v;
    v[0]=(short)f2bf(f0.x); v[1]=(short)f2bf(f0.y); v[2]=(short)f2bf(f0.z); v[3]=(short)f2bf(f0.w);
    v[4]=(short)f2bf(f1.x); v[5]=(short)f2bf(f1.y); v[6]=(short)f2bf(f1.z); v[7]=(short)f2bf(f1.w);
    *(short8*)&wihB[(size_t)gid*8] = v;
}

// ---------------- Layer 0: r6-verbatim (100 blocks x 256 threads) ----------------
__global__ __launch_bounds__(256, 1)
void lstm0_persist(const float* __restrict__ seq, const float* __restrict__ wih0,
                   const float* __restrict__ whh0, const float* __restrict__ bias,
                   u16* __restrict__ h0f, int* __restrict__ flags)
{
    __shared__ __align__(16) float part[4096];
    __shared__ __align__(16) u16 stageB[25600];
    __shared__ __align__(16) float w0l[64*48];
    __shared__ __align__(16) float xsl[2][32*48];
    __shared__ u16 hpk[2][NB*8];
    const int tid = threadIdx.x;
    const int d = blockIdx.x / NCH0, ch = blockIdx.x % NCH0;
    const int w = tid >> 6, l = tid & 63;
    const int p = w & 1, hl = w >> 1;
    int* myflags = flags + d*128;

    short8 wreg[2][25];
    {
        const int m = l & 15, g = p*2 + (m>>3);
#pragma unroll
        for (int T = 0; T < 2; ++T) {
            const int j = (ch*2 + T)*8 + (m&7);
            const float* base = whh0 + ((size_t)(d*G4_ + g*HID_ + j))*HID_ + (l>>4)*8;
#pragma unroll
            for (int kc = 0; kc < 25; ++kc) {
                float4 f0 = *(const float4*)(base + kc*32);
                float4 f1 = *(const float4*)(base + kc*32 + 4);
                short8 v;
                v[0]=cvt_hl(f0.x,hl); v[1]=cvt_hl(f0.y,hl); v[2]=cvt_hl(f0.z,hl); v[3]=cvt_hl(f0.w,hl);
                v[4]=cvt_hl(f1.x,hl); v[5]=cvt_hl(f1.y,hl); v[6]=cvt_hl(f1.z,hl); v[7]=cvt_hl(f1.w,hl);
                wreg[T][kc] = v;
            }
        }
    }
    for (int idx = tid; idx < 64*EMB_; idx += 256) {
        int r = idx / EMB_, k = idx % EMB_;
        int ju_ = r >> 2, g = r & 3;
        w0l[r*48 + k] = wih0[((size_t)(d*G4_ + g*HID_ + ch*16 + ju_))*IN0_ + k];
    }
    const int ju = tid >> 5, b = tid & 31;
    const int nt = b >> 4, n = b & 15;
    float biasr[2][4], wpos[2][4];
#pragma unroll
    for (int T = 0; T < 2; ++T) {
        const int j = ch*16 + T*8 + ju;
#pragma unroll
        for (int g = 0; g < 4; ++g) {
            biasr[T][g] = bias[d*G4_ + g*HID_ + j];
            wpos[T][g]  = wih0[((size_t)(d*G4_ + g*HID_ + j))*IN0_ + EMB_];
        }
    }
    float creg[2] = {0.f, 0.f};
    __syncthreads();

    for (int s = 0; s < T_LEN; ++s) {
        const int t = d ? (T_LEN-1-s) : s;

        for (int idx = tid; idx < 32*EMB_; idx += 256)
            xsl[s&1][(idx/EMB_)*48 + idx%EMB_] = seq[(size_t)t*(NB*EMB_) + idx];

        if (s > 0 && tid < NCH0)
            while (afload(myflags + tid) < s) __builtin_amdgcn_s_sleep(1);
        __syncthreads();

        if (s == 0) {
#pragma unroll
            for (int q = 0; q < 25; ++q) ((u64*)stageB)[tid + q*256] = 0ull;
        } else {
            const int tprev = d ? (T_LEN - s) : (s - 1);
            const u64* src = (const u64*)(h0f + (size_t)tprev*51200) + d*6400;
            u64 tmp[25];
#pragma unroll
            for (int q = 0; q < 25; ++q) tmp[q] = src[tid + q*256];
#pragma unroll
            for (int q = 0; q < 25; ++q) ((u64*)stageB)[tid + q*256] = tmp[q];
        }
        __syncthreads();   // B

        f32x4 a00 = {0.f,0.f,0.f,0.f}, a01 = {0.f,0.f,0.f,0.f};
        f32x4 a10 = {0.f,0.f,0.f,0.f}, a11 = {0.f,0.f,0.f,0.f};
#pragma unroll
        for (int kc = 0; kc < 25; ++kc) {
            short8 b0 = *(const short8*)(stageB + kc*1024 + l*8);
            short8 b1 = *(const short8*)(stageB + kc*1024 + 512 + l*8);
            a00 = mfma16(wreg[0][kc], b0, a00);
            a01 = mfma16(wreg[0][kc], b1, a01);
            a10 = mfma16(wreg[1][kc], b0, a10);
            a11 = mfma16(wreg[1][kc], b1, a11);
        }
        {
            const int mrow = (l>>4)*4, nn = l & 15;
#pragma unroll
            for (int r = 0; r < 4; ++r) {
                part[((0*8 + (p*2+hl)*2 + 0)*16 + mrow + r)*16 + nn] = a00[r];
                part[((0*8 + (p*2+hl)*2 + 1)*16 + mrow + r)*16 + nn] = a01[r];
                part[((1*8 + (p*2+hl)*2 + 0)*16 + mrow + r)*16 + nn] = a10[r];
                part[((1*8 + (p*2+hl)*2 + 1)*16 + mrow + r)*16 + nn] = a11[r];
            }
        }
        __syncthreads();   // C

#pragma unroll
        for (int T = 0; T < 2; ++T) {
            float dot0 = 0.f, dot1 = 0.f, dot2 = 0.f, dot3 = 0.f;
            const float* wr = &w0l[(T*8 + ju)*4*48];
            const float* xr = &xsl[s&1][b*48];
#pragma unroll
            for (int k4 = 0; k4 < 40; k4 += 4) {
                float4 xk = *(const float4*)(xr + k4);
                float4 w0 = *(const float4*)(wr + 0*48 + k4);
                float4 w1 = *(const float4*)(wr + 1*48 + k4);
                float4 w2 = *(const float4*)(wr + 2*48 + k4);
                float4 w3 = *(const float4*)(wr + 3*48 + k4);
                dot0 += w0.x*xk.x + w0.y*xk.y + w0.z*xk.z + w0.w*xk.w;
                dot1 += w1.x*xk.x + w1.y*xk.y + w1.z*xk.z + w1.w*xk.w;
                dot2 += w2.x*xk.x + w2.y*xk.y + w2.z*xk.z + w2.w*xk.w;
                dot3 += w3.x*xk.x + w3.y*xk.y + w3.z*xk.z + w3.w*xk.w;
            }
            float xk = xr[40];
            dot0 += wr[0*48+40]*xk; dot1 += wr[1*48+40]*xk;
            dot2 += wr[2*48+40]*xk; dot3 += wr[3*48+40]*xk;
            float v[4] = {dot0, dot1, dot2, dot3};
#pragma unroll
            for (int g = 0; g < 4; ++g) {
                const int pp = g >> 1, m = (g & 1)*8 + ju;
                v[g] += part[((T*8 + (pp*2+0)*2 + nt)*16 + m)*16 + n]
                      + part[((T*8 + (pp*2+1)*2 + nt)*16 + m)*16 + n]
                      + biasr[T][g] + (float)t * wpos[T][g];
            }
            float ig = 1.f/(1.f + expf(-v[0]));
            float fg = 1.f/(1.f + expf(-v[1]));
            float gg = tanhf(v[2]);
            float og = 1.f/(1.f + expf(-v[3]));
            creg[T] = fg * creg[T] + ig * gg;
            hpk[T][b*8 + ju] = f2bf(og * tanhf(creg[T]));
        }
        __syncthreads();   // D

        if (tid < 128) {
            const int T = tid >> 6, tl = tid & 63;
            const int bb = tl >> 1, half = tl & 1;
            const u16* hp = &hpk[T][bb*8 + half*4];
            u64 pk = (u64)hp[0] | ((u64)hp[1]<<16) | ((u64)hp[2]<<32) | ((u64)hp[3]<<48);
            const int ch2 = ch*2 + T;
            const int ntb = bb >> 4, llb = ((ch2&3)<<4) | (bb&15);
            const int xoff = ((d*25 + (ch2>>2))*2 + ntb)*128 + llb*2 + half;
            astore((u64*)(h0f + (size_t)t*51200) + xoff, pk);
        }
        __syncthreads();   // E
        if (tid == 0) afstore(myflags + ch, s+1);
    }
}

// ---------------- Layer 1: 200 blocks x 256 threads, xstage-LDS design ----------------
__global__ __launch_bounds__(256, 1)
void lstm1_persist(const float* __restrict__ whh1, const float* __restrict__ bias,
                   const float* __restrict__ lin_w, const u16* __restrict__ h0f,
                   const u16* __restrict__ wihB, u16* __restrict__ h1f,
                   int* __restrict__ flags, float* __restrict__ logits)
{
    __shared__ __align__(16) u16 xstage[51200];         // 100 KiB: h0f[t] full slab
    __shared__ __align__(16) u16 stageB[25600];         // 50 KiB: h1(s-1) slab
    __shared__ __align__(16) float part[2048];          // 8 KiB
    __shared__ u16 hpk[NB*8];                           // 0.5 KiB  => 162304 B total
    const int tid = threadIdx.x;
    const int d = blockIdx.x / NCH, ch = blockIdx.x % NCH;
    const int w = tid >> 6, l = tid & 63;
    const int p = w & 1, hl = w >> 1;
    int* myflags = flags + d*128;

    short8 wreg[25];   // whh1 hi/lo A-frags
    {
        const int m = l & 15, g = p*2 + (m>>3), j = ch*8 + (m&7);
        const float* base = whh1 + ((size_t)(d*G4_ + g*HID_ + j))*HID_ + (l>>4)*8;
#pragma unroll
        for (int kc = 0; kc < 25; ++kc) {
            float4 f0 = *(const float4*)(base + kc*32);
            float4 f1 = *(const float4*)(base + kc*32 + 4);
            short8 v;
            v[0]=cvt_hl(f0.x,hl); v[1]=cvt_hl(f0.y,hl); v[2]=cvt_hl(f0.z,hl); v[3]=cvt_hl(f0.w,hl);
            v[4]=cvt_hl(f1.x,hl); v[5]=cvt_hl(f1.y,hl); v[6]=cvt_hl(f1.z,hl); v[7]=cvt_hl(f1.w,hl);
            wreg[kc] = v;
        }
    }
    // x-GEMM A-frag base (global; values identical to r1's wihL)
    const u16* wb = wihB + ((size_t)((d*100 + ch)*2 + p)*50)*512;

    // logit-owner constants (wlin streamed from L2 per use; no register copy)
    const int ol = tid >> 5, ln = tid & 31;
    const int lo = ch*7 + ol;
    const bool lown = (ol < 7) && (lo < NB*NU);
    int lofs = 0;
    const float* wrow = lin_w;
    if (lown) {
        const int bb = lo / NU, uu = lo % NU;
        lofs = (bb >> 4)*512 + ((((ln >> 3) << 4) | (bb & 15)))*8 + (ln & 7);
        wrow = lin_w + (size_t)uu*IN1_ + d*HID_ + ln;
    }
    const int ju = tid >> 5, b = tid & 31;
    const int j = ch*8 + ju;
    const int nt = b >> 4, n = b & 15;
    float biasr[4];
#pragma unroll
    for (int g = 0; g < 4; ++g) biasr[g] = bias[d*G4_ + g*HID_ + j];
    float creg = 0.f;
    __syncthreads();

    for (int s = 0; s < T_LEN; ++s) {
        const int t = d ? (T_LEN-1-s) : s;
        const u64* xsrc = (const u64*)(h0f + (size_t)t*51200);   // 12800 u64

        // 1. issue x slab first half (prior-dispatch data; overlaps the poll)
        u64 xa[25];
#pragma unroll
        for (int q = 0; q < 25; ++q) xa[q] = xsrc[tid + q*256];

        // 2. poll + rendezvous
        if (s > 0 && tid < NCH)
            while (afload(myflags + tid) < s) __builtin_amdgcn_s_sleep(1);
        __syncthreads();   // A

        // 3. issue h1 stage burst (overlaps x half-1 latency)
        u64 st[25];
        if (s > 0) {
            const int tprev = d ? (T_LEN - s) : (s - 1);
            const u64* src = (const u64*)(h1f + (size_t)tprev*51200) + d*6400;
#pragma unroll
            for (int q = 0; q < 25; ++q) st[q] = src[tid + q*256];
        }
        // 4. write x half-1; 5. issue x half-2; 6. write stage; 7. write x half-2
#pragma unroll
        for (int q = 0; q < 25; ++q) ((u64*)xstage)[tid + q*256] = xa[q];
#pragma unroll
        for (int q = 0; q < 25; ++q) xa[q] = xsrc[tid + (25+q)*256];
        if (s > 0) {
#pragma unroll
            for (int q = 0; q < 25; ++q) ((u64*)stageB)[tid + q*256] = st[q];
        } else {
#pragma unroll
            for (int q = 0; q < 25; ++q) ((u64*)stageB)[tid + q*256] = 0ull;
        }
#pragma unroll
        for (int q = 0; q < 25; ++q) ((u64*)xstage)[tid + (25+q)*256] = xa[q];
        __syncthreads();   // B

        // MFMA: x-GEMM (A from L2-hot wihB, B from xstage) then h-GEMM — r1 order
        f32x4 acc0 = {0.f,0.f,0.f,0.f}, acc1 = {0.f,0.f,0.f,0.f};
#pragma unroll 5
        for (int kc = 0; kc < 25; ++kc) {
            const int idx = hl*25 + kc;
            short8 a  = *(const short8*)(wb + idx*512 + l*8);
            short8 b0 = *(const short8*)(xstage + idx*1024 + l*8);
            short8 b1 = *(const short8*)(xstage + idx*1024 + 512 + l*8);
            acc0 = mfma16(a, b0, acc0);
            acc1 = mfma16(a, b1, acc1);
        }
#pragma unroll 5
        for (int kc = 0; kc < 25; ++kc) {
            short8 b0 = *(const short8*)(stageB + kc*1024 + l*8);
            short8 b1 = *(const short8*)(stageB + kc*1024 + 512 + l*8);
            acc0 = mfma16(wreg[kc], b0, acc0);
            acc1 = mfma16(wreg[kc], b1, acc1);
        }
        {
            const int mrow = (l>>4)*4, nn = l & 15;
#pragma unroll
            for (int r = 0; r < 4; ++r) {
                part[(((p*2+hl)*2 + 0)*16 + mrow + r)*16 + nn] = acc0[r];
                part[(((p*2+hl)*2 + 1)*16 + mrow + r)*16 + nn] = acc1[r];
            }
        }
        __syncthreads();   // C

        float v[4];
#pragma unroll
        for (int g = 0; g < 4; ++g) {
            const int pp = g >> 1, m = (g & 1)*8 + ju;
            v[g] = part[(((pp*2+0)*2 + nt)*16 + m)*16 + n]
                 + part[(((pp*2+1)*2 + nt)*16 + m)*16 + n] + biasr[g];
        }
        float ig = 1.f/(1.f + expf(-v[0]));
        float fg = 1.f/(1.f + expf(-v[1]));
        float gg = tanhf(v[2]);
        float og = 1.f/(1.f + expf(-v[3]));
        creg = fg * creg + ig * gg;
        float hn = og * tanhf(creg);
        hpk[b*8 + ju] = f2bf(hn);
        __syncthreads();   // D

        if (tid < 64) {
            const int bb = tid >> 1, half = tid & 1;
            const u16* hp = &hpk[bb*8 + half*4];
            u64 pk = (u64)hp[0] | ((u64)hp[1]<<16) | ((u64)hp[2]<<32) | ((u64)hp[3]<<48);
            const int ntb = bb >> 4, llb = ((ch&3)<<4) | (bb&15);
            const int xoff = ((d*25 + (ch>>2))*2 + ntb)*128 + llb*2 + half;
            astore((u64*)(h1f + (size_t)t*51200) + xoff, pk);
        }
        __syncthreads();   // E: drain h stores
        if (tid == 0) afstore(myflags + ch, s+1);

        // distributed logits for h(tprev) from stageB; lin_w streamed from L2
        if (s > 0 && lown) {
            float sum = 0.f;
#pragma unroll
            for (int i = 0; i < 25; ++i)
                sum += bf2f(stageB[i*1024 + lofs]) * wrow[i*32];
#pragma unroll
            for (int off2 = 16; off2; off2 >>= 1) sum += __shfl_down(sum, off2, 32);
            if (ln == 0) {
                const int tprev = d ? (T_LEN - s) : (s - 1);
                logits[((size_t)d*T_LEN + tprev)*640 + lo] = sum;
            }
        }
    }
    // tail: logits for the final h
    if (tid < NCH)
        while (afload(myflags + tid) < T_LEN) __builtin_amdgcn_s_sleep(1);
    __syncthreads();
    {
        const int tlast = d ? 0 : (T_LEN - 1);
        const u64* src = (const u64*)(h1f + (size_t)tlast*51200) + d*6400;
        u64 tmp[25];
#pragma unroll
        for (int q = 0; q < 25; ++q) tmp[q] = src[tid + q*256];
#pragma unroll
        for (int q = 0; q < 25; ++q) ((u64*)stageB)[tid + q*256] = tmp[q];
    }
    __syncthreads();
    if (lown) {
        float sum = 0.f;
#pragma unroll
        for (int i = 0; i < 25; ++i)
            sum += bf2f(stageB[i*1024 + lofs]) * wrow[i*32];
#pragma unroll
        for (int off2 = 16; off2; off2 >>= 1) sum += __shfl_down(sum, off2, 32);
        if (ln == 0) {
            const int tprev = d ? 0 : (T_LEN - 1);
            logits[((size_t)d*T_LEN + tprev)*640 + lo] = sum;
        }
    }
}

// ---- sum dirs + lin_b -> softmax -> alphabet sin/cos mix; store (cosP, sinP) ----
__global__ __launch_bounds__(256)
void epilogue(const float* __restrict__ logits, const float* __restrict__ lin_b,
              const float* __restrict__ alphabet, float* __restrict__ cs)
{
    __shared__ float sa[NU*3], ca[NU*3], lb[NU];
    const int tid = threadIdx.x;
    if (tid < NU*3) { float al = alphabet[tid]; sa[tid] = sinf(al); ca[tid] = cosf(al); }
    if (tid < NU) lb[tid] = lin_b[tid];
    __syncthreads();
    const int row = blockIdx.x*256 + tid;   // t*NB + b
    if (row >= T_LEN*NB) return;
    const int t = row >> 5, b = row & 31;
    float lg[NU];
    float m = -1e30f;
#pragma unroll 4
    for (int u = 0; u < NU; ++u) {
        lg[u] = lb[u] + logits[(size_t)t*640 + b*NU + u]
                      + logits[((size_t)T_LEN + t)*640 + b*NU + u];
        m = fmaxf(m, lg[u]);
    }
    float ssum = 0.f;
#pragma unroll 4
    for (int u = 0; u < NU; ++u) { lg[u] = expf(lg[u] - m); ssum += lg[u]; }
    float inv = 1.f / ssum;
#pragma unroll
    for (int i = 0; i < 3; ++i) {
        float sv = 0.f, cv = 0.f;
#pragma unroll 4
        for (int u = 0; u < NU; ++u) {
            float sw = lg[u] * inv;
            sv += sw * sa[u*3 + i];
            cv += sw * ca[u*3 + i];
        }
        float rinv = rsqrtf(fmaxf(sv*sv + cv*cv, 1e-30f));
        *(float2*)(cs + ((size_t)row*3 + i)*2) = make_float2(cv*rinv, sv*rinv);
    }
}

// ---- sequential chain extension: one lane per molecule ----
__global__ __launch_bounds__(64)
void geometry(const float* __restrict__ cs, float* __restrict__ out)
{
    const int b = threadIdx.x;
    if (b >= NB) return;
    const float blen[3] = {1.329f, 1.459f, 1.525f};
    const float bang[3] = {2.034f, 2.119f, 1.937f};
    float sT[3], cT[3];
#pragma unroll
    for (int i = 0; i < 3; ++i) { sT[i] = sinf(bang[i]); cT[i] = cosf(bang[i]); }

    float Ax=0.f,Ay=0.f,Az=1.f, Bx=0.f,By=1.f,Bz=0.f, Cx=1.f,Cy=0.f,Cz=0.f;
    out[(0*NB + b)*3 + 0] = 0.f; out[(0*NB + b)*3 + 1] = 0.f; out[(0*NB + b)*3 + 2] = 1.f;
    out[(1*NB + b)*3 + 0] = 0.f; out[(1*NB + b)*3 + 1] = 1.f; out[(1*NB + b)*3 + 2] = 0.f;
    out[(2*NB + b)*3 + 0] = 1.f; out[(2*NB + b)*3 + 1] = 0.f; out[(2*NB + b)*3 + 2] = 0.f;

    for (int t = 1; t < T_LEN; ++t) {
        float2 pc[3];
#pragma unroll
        for (int i = 0; i < 3; ++i)
            pc[i] = *(const float2*)(cs + (((size_t)t*NB + b)*3 + i)*2);
#pragma unroll
        for (int i = 0; i < 3; ++i) {
            float R = blen[i];
            float d2x = -R*cT[i], d2y = R*pc[i].x*sT[i], d2z = R*pc[i].y*sT[i];
            float bcx = Cx-Bx, bcy = Cy-By, bcz = Cz-Bz;
            float inv = rsqrtf(bcx*bcx + bcy*bcy + bcz*bcz);
            bcx *= inv; bcy *= inv; bcz *= inv;
            float abx = Bx-Ax, aby = By-Ay, abz = Bz-Az;
            float nx = aby*bcz - abz*bcy;
            float ny = abz*bcx - abx*bcz;
            float nz = abx*bcy - aby*bcx;
            inv = rsqrtf(fmaxf(nx*nx + ny*ny + nz*nz, 1e-30f));
            nx *= inv; ny *= inv; nz *= inv;
            float mx = ny*bcz - nz*bcy;
            float my = nz*bcx - nx*bcz;
            float mz = nx*bcy - ny*bcx;
            float Dx = bcx*d2x + mx*d2y + nx*d2z + Cx;
            float Dy = bcy*d2x + my*d2y + ny*d2z + Cy;
            float Dz = bcz*d2x + mz*d2y + nz*d2z + Cz;
            Ax=Bx; Ay=By; Az=Bz; Bx=Cx; By=Cy; Bz=Cz; Cx=Dx; Cy=Dy; Cz=Dz;
            const int r = 3 + (t-1)*3 + i;
            out[((size_t)r*NB + b)*3 + 0] = Dx;
            out[((size_t)r*NB + b)*3 + 1] = Dy;
            out[((size_t)r*NB + b)*3 + 2] = Dz;
        }
    }
}

extern "C" void kernel_launch(void* const* d_in, const int* in_sizes, int n_in,
                              void* d_out, int out_size, void* d_ws, size_t ws_size,
                              hipStream_t stream)
{
    (void)in_sizes; (void)n_in; (void)out_size; (void)ws_size;
    const float* seq   = (const float*)d_in[0];
    const float* w_ih0 = (const float*)d_in[2];
    const float* w_hh0 = (const float*)d_in[3];
    const float* b0    = (const float*)d_in[4];
    const float* w_ih1 = (const float*)d_in[5];
    const float* w_hh1 = (const float*)d_in[6];
    const float* b1    = (const float*)d_in[7];
    const float* lin_w = (const float*)d_in[8];
    const float* lin_b = (const float*)d_in[9];
    const float* alpha = (const float*)d_in[10];

    // workspace (~128.4 MB)
    char* ws = (char*)d_ws;
    size_t off = 0;
    u16* h0f    = (u16*)(ws + off); off += 52428800ull;   // per-t write-once ring
    u16* h1f    = (u16*)(ws + off); off += 52428800ull;   // per-t write-once ring
    u16* wihB   = (u16*)(ws + off); off += 20480000ull;   // bf16 A-frag copy of w_ih1
    int* flagsL0 = (int*)(ws + off); off += 1024ull;      // 2 dirs x 128 ints
    int* flagsL1 = (int*)(ws + off); off += 1024ull;
    float* logits = (float*)(ws + off); off += 2621440ull;
    float* cs = (float*)(ws + off); off += 393216ull;

    hipMemsetAsync(flagsL0, 0, 2048, stream);   // both flag arrays

    wihb_init<<<dim3(5000), dim3(256), 0, stream>>>(w_ih1, wihB);

    lstm0_persist<<<dim3(2*NCH0), dim3(256), 0, stream>>>(seq, w_ih0, w_hh0, b0, h0f, flagsL0);

    lstm1_persist<<<dim3(2*NCH), dim3(256), 0, stream>>>(w_hh1, b1, lin_w, h0f, wihB, h1f,
                                                         flagsL1, logits);

    epilogue<<<dim3(64), dim3(256), 0, stream>>>(logits, lin_b, alpha, cs);
    geometry<<<dim3(1), dim3(64), 0, stream>>>(cs, (float*)d_out);
}

// Round 10
// 9326.240 us; speedup vs baseline: 1.4725x; 1.3158x over previous
//
#include <hip/hip_runtime.h>
#include <math.h>

#define T_LEN 512
#define NB    32
#define EMB_  41
#define IN0_  42
#define HID_  800
#define G4_   3200
#define IN1_  1600
#define NU    20
#define NCH0  50    // layer-0 blocks per direction
#define NCH   100   // layer-1 consumer blocks per direction

typedef unsigned short u16;
typedef unsigned int   u32;
typedef unsigned long long u64;
typedef __attribute__((ext_vector_type(8))) short short8;
typedef __attribute__((ext_vector_type(4))) float f32x4;

__device__ __forceinline__ float bf2f(u16 v) {
    union { u32 u; float f; } c; c.u = ((u32)v) << 16; return c.f;
}
__device__ __forceinline__ u16 f2bf(float f) {
    union { float f; u32 u; } c; c.f = f;
    u32 r = (c.u + 0x7fffu + ((c.u >> 16) & 1u)) >> 16;
    return (u16)r;
}
__device__ __forceinline__ short cvt_hl(float v, int hl) {
    u16 hi = f2bf(v);
    return hl ? (short)f2bf(v - bf2f(hi)) : (short)hi;
}
__device__ __forceinline__ f32x4 mfma16(short8 a, short8 b, f32x4 c) {
    return __builtin_amdgcn_mfma_f32_16x16x32_bf16(a, b, c, 0, 0, 0);
}
__device__ __forceinline__ void astore(u64* p, u64 v) {
    __hip_atomic_store(p, v, __ATOMIC_RELAXED, __HIP_MEMORY_SCOPE_AGENT);
}
__device__ __forceinline__ int afload(const int* p) {
    return __hip_atomic_load(p, __ATOMIC_RELAXED, __HIP_MEMORY_SCOPE_AGENT);
}
__device__ __forceinline__ void afstore(int* p, int v) {
    __hip_atomic_store(p, v, __ATOMIC_RELAXED, __HIP_MEMORY_SCOPE_AGENT);
}

// Round-10 (fast path, gated on ws_size):
//  * lstm0: r6-verbatim (best proven).
//  * lstm1: 400 blocks = 200 x-PRODUCERS (blockIdx 0..199, dispatched first)
//    + 200 slim consumers. Producers depend ONLY on prior-dispatch h0f: they
//    sweep t unthrottled (~1 us/t, 4-8x consumer pace), computing the REDUCED
//    per-thread x gate partial xv[4] (identical MFMA chain + part-reduction as
//    r1's x phase; only the final x-sum + h-sum f32 add order changes, ~1e-7)
//    into a write-once 419 MB buffer (agent-scope coalesced stores + flag).
//    Consumers = r6-lstm1 minus wihL/x-GEMM: LDS 59.9 KB -> 2 blocks/CU, all
//    400 resident (no deadlock); per step they poll {h1 flags, own producer
//    flag (always ahead)} then add xv in the gate phase.
//  * If ws_size < needed: launch the r6-proven lstm1 instead (zero risk).

// ---------------- Layer 0: r6-verbatim (100 blocks x 256 threads) ----------------
__global__ __launch_bounds__(256, 1)
void lstm0_persist(const float* __restrict__ seq, const float* __restrict__ wih0,
                   const float* __restrict__ whh0, const float* __restrict__ bias,
                   u16* __restrict__ h0f, int* __restrict__ flags)
{
    __shared__ __align__(16) float part[4096];
    __shared__ __align__(16) u16 stageB[25600];
    __shared__ __align__(16) float w0l[64*48];
    __shared__ __align__(16) float xsl[2][32*48];
    __shared__ u16 hpk[2][NB*8];
    const int tid = threadIdx.x;
    const int d = blockIdx.x / NCH0, ch = blockIdx.x % NCH0;
    const int w = tid >> 6, l = tid & 63;
    const int p = w & 1, hl = w >> 1;
    int* myflags = flags + d*128;

    short8 wreg[2][25];
    {
        const int m = l & 15, g = p*2 + (m>>3);
#pragma unroll
        for (int T = 0; T < 2; ++T) {
            const int j = (ch*2 + T)*8 + (m&7);
            const float* base = whh0 + ((size_t)(d*G4_ + g*HID_ + j))*HID_ + (l>>4)*8;
#pragma unroll
            for (int kc = 0; kc < 25; ++kc) {
                float4 f0 = *(const float4*)(base + kc*32);
                float4 f1 = *(const float4*)(base + kc*32 + 4);
                short8 v;
                v[0]=cvt_hl(f0.x,hl); v[1]=cvt_hl(f0.y,hl); v[2]=cvt_hl(f0.z,hl); v[3]=cvt_hl(f0.w,hl);
                v[4]=cvt_hl(f1.x,hl); v[5]=cvt_hl(f1.y,hl); v[6]=cvt_hl(f1.z,hl); v[7]=cvt_hl(f1.w,hl);
                wreg[T][kc] = v;
            }
        }
    }
    for (int idx = tid; idx < 64*EMB_; idx += 256) {
        int r = idx / EMB_, k = idx % EMB_;
        int ju_ = r >> 2, g = r & 3;
        w0l[r*48 + k] = wih0[((size_t)(d*G4_ + g*HID_ + ch*16 + ju_))*IN0_ + k];
    }
    const int ju = tid >> 5, b = tid & 31;
    const int nt = b >> 4, n = b & 15;
    float biasr[2][4], wpos[2][4];
#pragma unroll
    for (int T = 0; T < 2; ++T) {
        const int j = ch*16 + T*8 + ju;
#pragma unroll
        for (int g = 0; g < 4; ++g) {
            biasr[T][g] = bias[d*G4_ + g*HID_ + j];
            wpos[T][g]  = wih0[((size_t)(d*G4_ + g*HID_ + j))*IN0_ + EMB_];
        }
    }
    float creg[2] = {0.f, 0.f};
    __syncthreads();

    for (int s = 0; s < T_LEN; ++s) {
        const int t = d ? (T_LEN-1-s) : s;

        for (int idx = tid; idx < 32*EMB_; idx += 256)
            xsl[s&1][(idx/EMB_)*48 + idx%EMB_] = seq[(size_t)t*(NB*EMB_) + idx];

        if (s > 0 && tid < NCH0)
            while (afload(myflags + tid) < s) __builtin_amdgcn_s_sleep(1);
        __syncthreads();

        if (s == 0) {
#pragma unroll
            for (int q = 0; q < 25; ++q) ((u64*)stageB)[tid + q*256] = 0ull;
        } else {
            const int tprev = d ? (T_LEN - s) : (s - 1);
            const u64* src = (const u64*)(h0f + (size_t)tprev*51200) + d*6400;
            u64 tmp[25];
#pragma unroll
            for (int q = 0; q < 25; ++q) tmp[q] = src[tid + q*256];
#pragma unroll
            for (int q = 0; q < 25; ++q) ((u64*)stageB)[tid + q*256] = tmp[q];
        }
        __syncthreads();   // B

        f32x4 a00 = {0.f,0.f,0.f,0.f}, a01 = {0.f,0.f,0.f,0.f};
        f32x4 a10 = {0.f,0.f,0.f,0.f}, a11 = {0.f,0.f,0.f,0.f};
#pragma unroll
        for (int kc = 0; kc < 25; ++kc) {
            short8 b0 = *(const short8*)(stageB + kc*1024 + l*8);
            short8 b1 = *(const short8*)(stageB + kc*1024 + 512 + l*8);
            a00 = mfma16(wreg[0][kc], b0, a00);
            a01 = mfma16(wreg[0][kc], b1, a01);
            a10 = mfma16(wreg[1][kc], b0, a10);
            a11 = mfma16(wreg[1][kc], b1, a11);
        }
        {
            const int mrow = (l>>4)*4, nn = l & 15;
#pragma unroll
            for (int r = 0; r < 4; ++r) {
                part[((0*8 + (p*2+hl)*2 + 0)*16 + mrow + r)*16 + nn] = a00[r];
                part[((0*8 + (p*2+hl)*2 + 1)*16 + mrow + r)*16 + nn] = a01[r];
                part[((1*8 + (p*2+hl)*2 + 0)*16 + mrow + r)*16 + nn] = a10[r];
                part[((1*8 + (p*2+hl)*2 + 1)*16 + mrow + r)*16 + nn] = a11[r];
            }
        }
        __syncthreads();   // C

#pragma unroll
        for (int T = 0; T < 2; ++T) {
            float dot0 = 0.f, dot1 = 0.f, dot2 = 0.f, dot3 = 0.f;
            const float* wr = &w0l[(T*8 + ju)*4*48];
            const float* xr = &xsl[s&1][b*48];
#pragma unroll
            for (int k4 = 0; k4 < 40; k4 += 4) {
                float4 xk = *(const float4*)(xr + k4);
                float4 w0 = *(const float4*)(wr + 0*48 + k4);
                float4 w1 = *(const float4*)(wr + 1*48 + k4);
                float4 w2 = *(const float4*)(wr + 2*48 + k4);
                float4 w3 = *(const float4*)(wr + 3*48 + k4);
                dot0 += w0.x*xk.x + w0.y*xk.y + w0.z*xk.z + w0.w*xk.w;
                dot1 += w1.x*xk.x + w1.y*xk.y + w1.z*xk.z + w1.w*xk.w;
                dot2 += w2.x*xk.x + w2.y*xk.y + w2.z*xk.z + w2.w*xk.w;
                dot3 += w3.x*xk.x + w3.y*xk.y + w3.z*xk.z + w3.w*xk.w;
            }
            float xk = xr[40];
            dot0 += wr[0*48+40]*xk; dot1 += wr[1*48+40]*xk;
            dot2 += wr[2*48+40]*xk; dot3 += wr[3*48+40]*xk;
            float v[4] = {dot0, dot1, dot2, dot3};
#pragma unroll
            for (int g = 0; g < 4; ++g) {
                const int pp = g >> 1, m = (g & 1)*8 + ju;
                v[g] += part[((T*8 + (pp*2+0)*2 + nt)*16 + m)*16 + n]
                      + part[((T*8 + (pp*2+1)*2 + nt)*16 + m)*16 + n]
                      + biasr[T][g] + (float)t * wpos[T][g];
            }
            float ig = 1.f/(1.f + expf(-v[0]));
            float fg = 1.f/(1.f + expf(-v[1]));
            float gg = tanhf(v[2]);
            float og = 1.f/(1.f + expf(-v[3]));
            creg[T] = fg * creg[T] + ig * gg;
            hpk[T][b*8 + ju] = f2bf(og * tanhf(creg[T]));
        }
        __syncthreads();   // D

        if (tid < 128) {
            const int T = tid >> 6, tl = tid & 63;
            const int bb = tl >> 1, half = tl & 1;
            const u16* hp = &hpk[T][bb*8 + half*4];
            u64 pk = (u64)hp[0] | ((u64)hp[1]<<16) | ((u64)hp[2]<<32) | ((u64)hp[3]<<48);
            const int ch2 = ch*2 + T;
            const int ntb = bb >> 4, llb = ((ch2&3)<<4) | (bb&15);
            const int xoff = ((d*25 + (ch2>>2))*2 + ntb)*128 + llb*2 + half;
            astore((u64*)(h0f + (size_t)t*51200) + xoff, pk);
        }
        __syncthreads();   // E
        if (tid == 0) afstore(myflags + ch, s+1);
    }
}

// ---------------- Layer 1 FAST: 400 blocks (200 producers + 200 slim consumers) ----------------
__global__ __launch_bounds__(256, 1)
void lstm1_fast(const float* __restrict__ whh1, const float* __restrict__ wih1,
                const float* __restrict__ bias, const float* __restrict__ lin_w,
                const u16* __restrict__ h0f, u16* __restrict__ h1f,
                float* __restrict__ xwv, int* __restrict__ flags,
                int* __restrict__ prodflag, float* __restrict__ logits)
{
    __shared__ __align__(16) u16 stageB[25600];         // 50 KiB
    __shared__ __align__(16) float part[2048];          // 8 KiB
    __shared__ u16 hpk[NB*8];                           // => 59904 B total
    const int tid = threadIdx.x;
    const int w = tid >> 6, l = tid & 63;
    const int p = w & 1, hl = w >> 1;
    const int ju = tid >> 5, b = tid & 31;
    const int nt = b >> 4, n = b & 15;

    // ================= x-producer role (blockIdx 0..199) =================
    if (blockIdx.x < 200) {
        const int dq = blockIdx.x / 100, ch = blockIdx.x % 100;
        short8 wregx[25];   // wih1 hi-only frags (values == r1's wihL)
        {
            const int m = l & 15, g = p*2 + (m>>3), jj = ch*8 + (m&7);
            const float* basew = wih1 + ((size_t)(dq*G4_ + g*HID_ + jj))*IN1_ + (l>>4)*8;
#pragma unroll
            for (int kc = 0; kc < 25; ++kc) {
                const int idx = hl*25 + kc;
                float4 f0 = *(const float4*)(basew + idx*32);
                float4 f1 = *(const float4*)(basew + idx*32 + 4);
                short8 v;
                v[0]=(short)f2bf(f0.x); v[1]=(short)f2bf(f0.y); v[2]=(short)f2bf(f0.z); v[3]=(short)f2bf(f0.w);
                v[4]=(short)f2bf(f1.x); v[5]=(short)f2bf(f1.y); v[6]=(short)f2bf(f1.z); v[7]=(short)f2bf(f1.w);
                wregx[kc] = v;
            }
        }
        int* pf = prodflag + blockIdx.x;
        for (int k = 0; k < T_LEN; ++k) {
            const int t = dq ? (T_LEN-1-k) : k;
            const u16* xb = h0f + (size_t)t*51200;   // prior-dispatch, L2-shared
            f32x4 a0 = {0.f,0.f,0.f,0.f}, a1 = {0.f,0.f,0.f,0.f};
#pragma unroll 5
            for (int kc = 0; kc < 25; ++kc) {
                const int idx = hl*25 + kc;
                short8 b0 = *(const short8*)(xb + idx*1024 + l*8);
                short8 b1 = *(const short8*)(xb + idx*1024 + 512 + l*8);
                a0 = mfma16(wregx[kc], b0, a0);
                a1 = mfma16(wregx[kc], b1, a1);
            }
            {
                const int mrow = (l>>4)*4, nn = l & 15;
#pragma unroll
                for (int r = 0; r < 4; ++r) {
                    part[(((p*2+hl)*2 + 0)*16 + mrow + r)*16 + nn] = a0[r];
                    part[(((p*2+hl)*2 + 1)*16 + mrow + r)*16 + nn] = a1[r];
                }
            }
            __syncthreads();
            union { float f[4]; u64 q[2]; } uo;
#pragma unroll
            for (int g = 0; g < 4; ++g) {
                const int pp = g >> 1, m = (g & 1)*8 + ju;
                uo.f[g] = part[(((pp*2+0)*2 + nt)*16 + m)*16 + n]
                        + part[(((pp*2+1)*2 + nt)*16 + m)*16 + n];
            }
            u64* dst = (u64*)xwv + ((((size_t)dq*100 + ch)*T_LEN + t)*256 + tid)*2;
            astore(dst, uo.q[0]);
            astore(dst + 1, uo.q[1]);
            __syncthreads();    // drains vmcnt (stores at LLC) + protects part
            if (tid == 0) afstore(pf, k+1);
        }
        return;
    }

    // ================= slim consumer role (blockIdx 200..399) =================
    const int d = (blockIdx.x - 200) / 100, ch = (blockIdx.x - 200) % 100;
    int* myflags = flags + d*128;
    const int* pf = prodflag + d*100 + ch;

    short8 wreg[25];   // whh1 hi/lo A-frags
    {
        const int m = l & 15, g = p*2 + (m>>3), j = ch*8 + (m&7);
        const float* base = whh1 + ((size_t)(d*G4_ + g*HID_ + j))*HID_ + (l>>4)*8;
#pragma unroll
        for (int kc = 0; kc < 25; ++kc) {
            float4 f0 = *(const float4*)(base + kc*32);
            float4 f1 = *(const float4*)(base + kc*32 + 4);
            short8 v;
            v[0]=cvt_hl(f0.x,hl); v[1]=cvt_hl(f0.y,hl); v[2]=cvt_hl(f0.z,hl); v[3]=cvt_hl(f0.w,hl);
            v[4]=cvt_hl(f1.x,hl); v[5]=cvt_hl(f1.y,hl); v[6]=cvt_hl(f1.z,hl); v[7]=cvt_hl(f1.w,hl);
            wreg[kc] = v;
        }
    }
    // logit-owner constants + register-resident lin_w (step-invariant)
    const int ol = tid >> 5, ln = tid & 31;
    const int lo = ch*7 + ol;
    const bool lown = (ol < 7) && (lo < NB*NU);
    int lofs = 0;
    float wlin[25];
    if (lown) {
        const int bb = lo / NU, uu = lo % NU;
        lofs = (bb >> 4)*512 + ((((ln >> 3) << 4) | (bb & 15)))*8 + (ln & 7);
        const float* wrow = lin_w + (size_t)uu*IN1_ + d*HID_ + ln;
#pragma unroll
        for (int i = 0; i < 25; ++i) wlin[i] = wrow[i*32];
    }
    const int j = ch*8 + ju;
    float biasr[4];
#pragma unroll
    for (int g = 0; g < 4; ++g) biasr[g] = bias[d*G4_ + g*HID_ + j];
    float creg = 0.f;
    __syncthreads();

    for (int s = 0; s < T_LEN; ++s) {
        const int t = d ? (T_LEN-1-s) : s;

        if (s > 0 && tid < NCH)
            while (afload(myflags + tid) < s) __builtin_amdgcn_s_sleep(1);
        if (tid == 128)     // producer is ~4-8x faster: hit rate ~100%
            while (afload(pf) < s+1) __builtin_amdgcn_s_sleep(1);
        __syncthreads();    // A

        // xv load (fresh address -> LLC-coherent) + h1 slab stage burst
        float4 xq = *(const float4*)(xwv + ((((size_t)d*100 + ch)*T_LEN + t)*256 + tid)*4);
        if (s == 0) {
#pragma unroll
            for (int q = 0; q < 25; ++q) ((u64*)stageB)[tid + q*256] = 0ull;
        } else {
            const int tprev = d ? (T_LEN - s) : (s - 1);
            const u64* src = (const u64*)(h1f + (size_t)tprev*51200) + d*6400;
            u64 tmp[25];
#pragma unroll
            for (int q = 0; q < 25; ++q) tmp[q] = src[tid + q*256];
#pragma unroll
            for (int q = 0; q < 25; ++q) ((u64*)stageB)[tid + q*256] = tmp[q];
        }
        __syncthreads();   // B

        f32x4 acc0 = {0.f,0.f,0.f,0.f}, acc1 = {0.f,0.f,0.f,0.f};
#pragma unroll 5
        for (int kc = 0; kc < 25; ++kc) {
            short8 b0 = *(const short8*)(stageB + kc*1024 + l*8);
            short8 b1 = *(const short8*)(stageB + kc*1024 + 512 + l*8);
            acc0 = mfma16(wreg[kc], b0, acc0);
            acc1 = mfma16(wreg[kc], b1, acc1);
        }
        {
            const int mrow = (l>>4)*4, nn = l & 15;
#pragma unroll
            for (int r = 0; r < 4; ++r) {
                part[(((p*2+hl)*2 + 0)*16 + mrow + r)*16 + nn] = acc0[r];
                part[(((p*2+hl)*2 + 1)*16 + mrow + r)*16 + nn] = acc1[r];
            }
        }
        __syncthreads();   // C

        float xqa[4] = {xq.x, xq.y, xq.z, xq.w};
        float v[4];
#pragma unroll
        for (int g = 0; g < 4; ++g) {
            const int pp = g >> 1, m = (g & 1)*8 + ju;
            v[g] = part[(((pp*2+0)*2 + nt)*16 + m)*16 + n]
                 + part[(((pp*2+1)*2 + nt)*16 + m)*16 + n] + xqa[g] + biasr[g];
        }
        float ig = 1.f/(1.f + expf(-v[0]));
        float fg = 1.f/(1.f + expf(-v[1]));
        float gg = tanhf(v[2]);
        float og = 1.f/(1.f + expf(-v[3]));
        creg = fg * creg + ig * gg;
        float hn = og * tanhf(creg);
        hpk[b*8 + ju] = f2bf(hn);
        __syncthreads();   // D

        if (tid < 64) {
            const int bb = tid >> 1, half = tid & 1;
            const u16* hp = &hpk[bb*8 + half*4];
            u64 pk = (u64)hp[0] | ((u64)hp[1]<<16) | ((u64)hp[2]<<32) | ((u64)hp[3]<<48);
            const int ntb = bb >> 4, llb = ((ch&3)<<4) | (bb&15);
            const int xoff = ((d*25 + (ch>>2))*2 + ntb)*128 + llb*2 + half;
            astore((u64*)(h1f + (size_t)t*51200) + xoff, pk);
        }
        __syncthreads();   // E: drain h stores
        if (tid == 0) afstore(myflags + ch, s+1);

        // distributed logits for h(tprev) from stageB (valid until next staging)
        if (s > 0 && lown) {
            float sum = 0.f;
#pragma unroll
            for (int i = 0; i < 25; ++i)
                sum += bf2f(stageB[i*1024 + lofs]) * wlin[i];
#pragma unroll
            for (int off2 = 16; off2; off2 >>= 1) sum += __shfl_down(sum, off2, 32);
            if (ln == 0) {
                const int tprev = d ? (T_LEN - s) : (s - 1);
                logits[((size_t)d*T_LEN + tprev)*640 + lo] = sum;
            }
        }
    }
    // tail: logits for the final h
    if (tid < NCH)
        while (afload(myflags + tid) < T_LEN) __builtin_amdgcn_s_sleep(1);
    __syncthreads();
    {
        const int tlast = d ? 0 : (T_LEN - 1);
        const u64* src = (const u64*)(h1f + (size_t)tlast*51200) + d*6400;
        u64 tmp[25];
#pragma unroll
        for (int q = 0; q < 25; ++q) tmp[q] = src[tid + q*256];
#pragma unroll
        for (int q = 0; q < 25; ++q) ((u64*)stageB)[tid + q*256] = tmp[q];
    }
    __syncthreads();
    if (lown) {
        float sum = 0.f;
#pragma unroll
        for (int i = 0; i < 25; ++i)
            sum += bf2f(stageB[i*1024 + lofs]) * wlin[i];
#pragma unroll
        for (int off2 = 16; off2; off2 >>= 1) sum += __shfl_down(sum, off2, 32);
        if (ln == 0) {
            const int tprev = d ? 0 : (T_LEN - 1);
            logits[((size_t)d*T_LEN + tprev)*640 + lo] = sum;
        }
    }
}

// ---------------- Layer 1 FALLBACK: r6-verbatim (200 blocks) ----------------
__global__ __launch_bounds__(256, 1)
void lstm1_persist(const float* __restrict__ wih1, const float* __restrict__ whh1,
                   const float* __restrict__ bias, const float* __restrict__ lin_w,
                   const u16* __restrict__ h0f, u16* __restrict__ h1f,
                   int* __restrict__ flags, float* __restrict__ logits)
{
    __shared__ __align__(16) u16 wihL[2*50*512];
    __shared__ __align__(16) u16 stageB[25600];
    __shared__ __align__(16) float part[2048];
    __shared__ u16 hpk[NB*8];
    const int tid = threadIdx.x;
    const int d = blockIdx.x / NCH, ch = blockIdx.x % NCH;
    const int w = tid >> 6, l = tid & 63;
    const int p = w & 1, hl = w >> 1;
    int* myflags = flags + d*128;

    short8 wreg[25];
    {
        const int m = l & 15, g = p*2 + (m>>3), j = ch*8 + (m&7);
        const float* base = whh1 + ((size_t)(d*G4_ + g*HID_ + j))*HID_ + (l>>4)*8;
#pragma unroll
        for (int kc = 0; kc < 25; ++kc) {
            float4 f0 = *(const float4*)(base + kc*32);
            float4 f1 = *(const float4*)(base + kc*32 + 4);
            short8 v;
            v[0]=cvt_hl(f0.x,hl); v[1]=cvt_hl(f0.y,hl); v[2]=cvt_hl(f0.z,hl); v[3]=cvt_hl(f0.w,hl);
            v[4]=cvt_hl(f1.x,hl); v[5]=cvt_hl(f1.y,hl); v[6]=cvt_hl(f1.z,hl); v[7]=cvt_hl(f1.w,hl);
            wreg[kc] = v;
        }
    }
    for (int o = tid; o < 6400; o += 256) {
        int pp = o / 3200, r = o % 3200, kc = r >> 6, ll = r & 63;
        int m = ll & 15, g = pp*2 + (m>>3), jj = ch*8 + (m&7);
        const float* base = wih1 + ((size_t)(d*G4_ + g*HID_ + jj))*IN1_ + kc*32 + (ll>>4)*8;
        float4 f0 = *(const float4*)base;
        float4 f1 = *(const float4*)(base + 4);
        short8 v;
        v[0]=(short)f2bf(f0.x); v[1]=(short)f2bf(f0.y); v[2]=(short)f2bf(f0.z); v[3]=(short)f2bf(f0.w);
        v[4]=(short)f2bf(f1.x); v[5]=(short)f2bf(f1.y); v[6]=(short)f2bf(f1.z); v[7]=(short)f2bf(f1.w);
        *(short8*)&wihL[o*8] = v;
    }
    const int ol = tid >> 5, ln = tid & 31;
    const int lo = ch*7 + ol;
    const bool lown = (ol < 7) && (lo < NB*NU);
    int lofs = 0;
    float wlin[25];
    if (lown) {
        const int bb = lo / NU, uu = lo % NU;
        lofs = (bb >> 4)*512 + ((((ln >> 3) << 4) | (bb & 15)))*8 + (ln & 7);
        const float* wrow = lin_w + (size_t)uu*IN1_ + d*HID_ + ln;
#pragma unroll
        for (int i = 0; i < 25; ++i) wlin[i] = wrow[i*32];
    }
    const int ju = tid >> 5, b = tid & 31;
    const int j = ch*8 + ju;
    const int nt = b >> 4, n = b & 15;
    float biasr[4];
#pragma unroll
    for (int g = 0; g < 4; ++g) biasr[g] = bias[d*G4_ + g*HID_ + j];
    float creg = 0.f;
    __syncthreads();

    for (int s = 0; s < T_LEN; ++s) {
        const int t = d ? (T_LEN-1-s) : s;

        f32x4 acc0 = {0.f,0.f,0.f,0.f}, acc1 = {0.f,0.f,0.f,0.f};
        {
            const u16* xb = h0f + (size_t)t*51200;
#pragma unroll 5
            for (int kc = 0; kc < 25; ++kc) {
                const int idx = hl*25 + kc;
                short8 a  = *(const short8*)&wihL[(p*50 + idx)*512 + l*8];
                short8 b0 = *(const short8*)(xb + idx*1024 + l*8);
                short8 b1 = *(const short8*)(xb + idx*1024 + 512 + l*8);
                acc0 = mfma16(a, b0, acc0);
                acc1 = mfma16(a, b1, acc1);
            }
        }

        if (s > 0 && tid < NCH)
            while (afload(myflags + tid) < s) __builtin_amdgcn_s_sleep(1);
        __syncthreads();

        if (s == 0) {
#pragma unroll
            for (int q = 0; q < 25; ++q) ((u64*)stageB)[tid + q*256] = 0ull;
        } else {
            const int tprev = d ? (T_LEN - s) : (s - 1);
            const u64* src = (const u64*)(h1f + (size_t)tprev*51200) + d*6400;
            u64 tmp[25];
#pragma unroll
            for (int q = 0; q < 25; ++q) tmp[q] = src[tid + q*256];
#pragma unroll
            for (int q = 0; q < 25; ++q) ((u64*)stageB)[tid + q*256] = tmp[q];
        }
        __syncthreads();

#pragma unroll 5
        for (int kc = 0; kc < 25; ++kc) {
            short8 b0 = *(const short8*)(stageB + kc*1024 + l*8);
            short8 b1 = *(const short8*)(stageB + kc*1024 + 512 + l*8);
            acc0 = mfma16(wreg[kc], b0, acc0);
            acc1 = mfma16(wreg[kc], b1, acc1);
        }
        {
            const int mrow = (l>>4)*4, nn = l & 15;
#pragma unroll
            for (int r = 0; r < 4; ++r) {
                part[(((p*2+hl)*2 + 0)*16 + mrow + r)*16 + nn] = acc0[r];
                part[(((p*2+hl)*2 + 1)*16 + mrow + r)*16 + nn] = acc1[r];
            }
        }
        __syncthreads();

        float v[4];
#pragma unroll
        for (int g = 0; g < 4; ++g) {
            const int pp = g >> 1, m = (g & 1)*8 + ju;
            v[g] = part[(((pp*2+0)*2 + nt)*16 + m)*16 + n]
                 + part[(((pp*2+1)*2 + nt)*16 + m)*16 + n] + biasr[g];
        }
        float ig = 1.f/(1.f + expf(-v[0]));
        float fg = 1.f/(1.f + expf(-v[1]));
        float gg = tanhf(v[2]);
        float og = 1.f/(1.f + expf(-v[3]));
        creg = fg * creg + ig * gg;
        float hn = og * tanhf(creg);
        hpk[b*8 + ju] = f2bf(hn);
        __syncthreads();

        if (tid < 64) {
            const int bb = tid >> 1, half = tid & 1;
            const u16* hp = &hpk[bb*8 + half*4];
            u64 pk = (u64)hp[0] | ((u64)hp[1]<<16) | ((u64)hp[2]<<32) | ((u64)hp[3]<<48);
            const int ntb = bb >> 4, llb = ((ch&3)<<4) | (bb&15);
            const int xoff = ((d*25 + (ch>>2))*2 + ntb)*128 + llb*2 + half;
            astore((u64*)(h1f + (size_t)t*51200) + xoff, pk);
        }
        __syncthreads();
        if (tid == 0) afstore(myflags + ch, s+1);

        if (s > 0 && lown) {
            float sum = 0.f;
#pragma unroll
            for (int i = 0; i < 25; ++i)
                sum += bf2f(stageB[i*1024 + lofs]) * wlin[i];
#pragma unroll
            for (int off2 = 16; off2; off2 >>= 1) sum += __shfl_down(sum, off2, 32);
            if (ln == 0) {
                const int tprev = d ? (T_LEN - s) : (s - 1);
                logits[((size_t)d*T_LEN + tprev)*640 + lo] = sum;
            }
        }
    }
    if (tid < NCH)
        while (afload(myflags + tid) < T_LEN) __builtin_amdgcn_s_sleep(1);
    __syncthreads();
    {
        const int tlast = d ? 0 : (T_LEN - 1);
        const u64* src = (const u64*)(h1f + (size_t)tlast*51200) + d*6400;
        u64 tmp[25];
#pragma unroll
        for (int q = 0; q < 25; ++q) tmp[q] = src[tid + q*256];
#pragma unroll
        for (int q = 0; q < 25; ++q) ((u64*)stageB)[tid + q*256] = tmp[q];
    }
    __syncthreads();
    if (lown) {
        float sum = 0.f;
#pragma unroll
        for (int i = 0; i < 25; ++i)
            sum += bf2f(stageB[i*1024 + lofs]) * wlin[i];
#pragma unroll
        for (int off2 = 16; off2; off2 >>= 1) sum += __shfl_down(sum, off2, 32);
        if (ln == 0) {
            const int tprev = d ? 0 : (T_LEN - 1);
            logits[((size_t)d*T_LEN + tprev)*640 + lo] = sum;
        }
    }
}

// ---- sum dirs + lin_b -> softmax -> alphabet sin/cos mix; store (cosP, sinP) ----
__global__ __launch_bounds__(256)
void epilogue(const float* __restrict__ logits, const float* __restrict__ lin_b,
              const float* __restrict__ alphabet, float* __restrict__ cs)
{
    __shared__ float sa[NU*3], ca[NU*3], lb[NU];
    const int tid = threadIdx.x;
    if (tid < NU*3) { float al = alphabet[tid]; sa[tid] = sinf(al); ca[tid] = cosf(al); }
    if (tid < NU) lb[tid] = lin_b[tid];
    __syncthreads();
    const int row = blockIdx.x*256 + tid;   // t*NB + b
    if (row >= T_LEN*NB) return;
    const int t = row >> 5, b = row & 31;
    float lg[NU];
    float m = -1e30f;
#pragma unroll 4
    for (int u = 0; u < NU; ++u) {
        lg[u] = lb[u] + logits[(size_t)t*640 + b*NU + u]
                      + logits[((size_t)T_LEN + t)*640 + b*NU + u];
        m = fmaxf(m, lg[u]);
    }
    float ssum = 0.f;
#pragma unroll 4
    for (int u = 0; u < NU; ++u) { lg[u] = expf(lg[u] - m); ssum += lg[u]; }
    float inv = 1.f / ssum;
#pragma unroll
    for (int i = 0; i < 3; ++i) {
        float sv = 0.f, cv = 0.f;
#pragma unroll 4
        for (int u = 0; u < NU; ++u) {
            float sw = lg[u] * inv;
            sv += sw * sa[u*3 + i];
            cv += sw * ca[u*3 + i];
        }
        float rinv = rsqrtf(fmaxf(sv*sv + cv*cv, 1e-30f));
        *(float2*)(cs + ((size_t)row*3 + i)*2) = make_float2(cv*rinv, sv*rinv);
    }
}

// ---- sequential chain extension: one lane per molecule ----
__global__ __launch_bounds__(64)
void geometry(const float* __restrict__ cs, float* __restrict__ out)
{
    const int b = threadIdx.x;
    if (b >= NB) return;
    const float blen[3] = {1.329f, 1.459f, 1.525f};
    const float bang[3] = {2.034f, 2.119f, 1.937f};
    float sT[3], cT[3];
#pragma unroll
    for (int i = 0; i < 3; ++i) { sT[i] = sinf(bang[i]); cT[i] = cosf(bang[i]); }

    float Ax=0.f,Ay=0.f,Az=1.f, Bx=0.f,By=1.f,Bz=0.f, Cx=1.f,Cy=0.f,Cz=0.f;
    out[(0*NB + b)*3 + 0] = 0.f; out[(0*NB + b)*3 + 1] = 0.f; out[(0*NB + b)*3 + 2] = 1.f;
    out[(1*NB + b)*3 + 0] = 0.f; out[(1*NB + b)*3 + 1] = 1.f; out[(1*NB + b)*3 + 2] = 0.f;
    out[(2*NB + b)*3 + 0] = 1.f; out[(2*NB + b)*3 + 1] = 0.f; out[(2*NB + b)*3 + 2] = 0.f;

    for (int t = 1; t < T_LEN; ++t) {
        float2 pc[3];
#pragma unroll
        for (int i = 0; i < 3; ++i)
            pc[i] = *(const float2*)(cs + (((size_t)t*NB + b)*3 + i)*2);
#pragma unroll
        for (int i = 0; i < 3; ++i) {
            float R = blen[i];
            float d2x = -R*cT[i], d2y = R*pc[i].x*sT[i], d2z = R*pc[i].y*sT[i];
            float bcx = Cx-Bx, bcy = Cy-By, bcz = Cz-Bz;
            float inv = rsqrtf(bcx*bcx + bcy*bcy + bcz*bcz);
            bcx *= inv; bcy *= inv; bcz *= inv;
            float abx = Bx-Ax, aby = By-Ay, abz = Bz-Az;
            float nx = aby*bcz - abz*bcy;
            float ny = abz*bcx - abx*bcz;
            float nz = abx*bcy - aby*bcx;
            inv = rsqrtf(fmaxf(nx*nx + ny*ny + nz*nz, 1e-30f));
            nx *= inv; ny *= inv; nz *= inv;
            float mx = ny*bcz - nz*bcy;
            float my = nz*bcx - nx*bcz;
            float mz = nx*bcy - ny*bcx;
            float Dx = bcx*d2x + mx*d2y + nx*d2z + Cx;
            float Dy = bcy*d2x + my*d2y + ny*d2z + Cy;
            float Dz = bcz*d2x + mz*d2y + nz*d2z + Cz;
            Ax=Bx; Ay=By; Az=Bz; Bx=Cx; By=Cy; Bz=Cz; Cx=Dx; Cy=Dy; Cz=Dz;
            const int r = 3 + (t-1)*3 + i;
            out[((size_t)r*NB + b)*3 + 0] = Dx;
            out[((size_t)r*NB + b)*3 + 1] = Dy;
            out[((size_t)r*NB + b)*3 + 2] = Dz;
        }
    }
}

extern "C" void kernel_launch(void* const* d_in, const int* in_sizes, int n_in,
                              void* d_out, int out_size, void* d_ws, size_t ws_size,
                              hipStream_t stream)
{
    (void)in_sizes; (void)n_in; (void)out_size;
    const float* seq   = (const float*)d_in[0];
    const float* w_ih0 = (const float*)d_in[2];
    const float* w_hh0 = (const float*)d_in[3];
    const float* b0    = (const float*)d_in[4];
    const float* w_ih1 = (const float*)d_in[5];
    const float* w_hh1 = (const float*)d_in[6];
    const float* b1    = (const float*)d_in[7];
    const float* lin_w = (const float*)d_in[8];
    const float* lin_b = (const float*)d_in[9];
    const float* alpha = (const float*)d_in[10];

    char* ws = (char*)d_ws;
    const bool fastp = (ws_size >= 530000000ull);   // need ~527.4 MB for xwv path

    if (fastp) {
        size_t off = 0;
        u16* h0f      = (u16*)(ws + off); off += 52428800ull;
        u16* h1f      = (u16*)(ws + off); off += 52428800ull;
        float* xwv    = (float*)(ws + off); off += 419430400ull;  // [d][ch][t][tid][4] f32
        int* flagsL0  = (int*)(ws + off); off += 1024ull;
        int* flagsL1  = (int*)(ws + off); off += 1024ull;
        int* prodflag = (int*)(ws + off); off += 1024ull;
        float* logits = (float*)(ws + off); off += 2621440ull;
        float* cs     = (float*)(ws + off); off += 393216ull;

        hipMemsetAsync(flagsL0, 0, 3072, stream);   // all three flag arrays

        lstm0_persist<<<dim3(2*NCH0), dim3(256), 0, stream>>>(seq, w_ih0, w_hh0, b0,
                                                              h0f, flagsL0);
        lstm1_fast<<<dim3(400), dim3(256), 0, stream>>>(w_hh1, w_ih1, b1, lin_w, h0f, h1f,
                                                        xwv, flagsL1, prodflag, logits);
        epilogue<<<dim3(64), dim3(256), 0, stream>>>(logits, lin_b, alpha, cs);
        geometry<<<dim3(1), dim3(64), 0, stream>>>(cs, (float*)d_out);
    } else {
        // r6-proven fallback (~107.9 MB)
        size_t off = 0;
        u16* h0f      = (u16*)(ws + off); off += 52428800ull;
        u16* h1f      = (u16*)(ws + off); off += 52428800ull;
        int* flagsL0  = (int*)(ws + off); off += 1024ull;
        int* flagsL1  = (int*)(ws + off); off += 1024ull;
        float* logits = (float*)(ws + off); off += 2621440ull;
        float* cs     = (float*)(ws + off); off += 393216ull;

        hipMemsetAsync(flagsL0, 0, 2048, stream);

        lstm0_persist<<<dim3(2*NCH0), dim3(256), 0, stream>>>(seq, w_ih0, w_hh0, b0,
                                                              h0f, flagsL0);
        lstm1_persist<<<dim3(2*NCH), dim3(256), 0, stream>>>(w_ih1, w_hh1, b1, lin_w,
                                                             h0f, h1f, flagsL1, logits);
        epilogue<<<dim3(64), dim3(256), 0, stream>>>(logits, lin_b, alpha, cs);
        geometry<<<dim3(1), dim3(64), 0, stream>>>(cs, (float*)d_out);
    }
}